// Round 6
// baseline (526.204 us; speedup 1.0000x reference)
//
#include <hip/hip_runtime.h>

#define D 128
#define OUTD 64
#define LAYERS 3

typedef __attribute__((ext_vector_type(8))) short short8;
typedef __attribute__((ext_vector_type(4))) float float4v;
typedef __attribute__((ext_vector_type(2))) float floatx2;
typedef unsigned int uint32;

static inline int ceil_div(int a, int b) { return (a + b - 1) / b; }

__device__ __forceinline__ unsigned short f2bf(float f) {
    unsigned int u = __float_as_uint(f);
    unsigned int r = u + 0x7FFFu + ((u >> 16) & 1u);
    return (unsigned short)(r >> 16);
}

// feature permutation: storage element position of logical feature f.
// Applied identically to all k-dim storages (xb, h, jk, wt rows, wlt rows,
// bcomb, t1b, t2q, t3q) -> GEMM dot products unchanged, epilogue stores
// become lane-contiguous.
__device__ __forceinline__ int fperm(int f) { return (f & 15) * 8 + (f >> 4); }

// ---------------- prep: XCD-partitioned degree count + all converts ----------------

#define CNT_BLOCKS 1280   // 8 node-range groups x 160 blocks
#define CVX_BLOCKS 1044

__global__ __launch_bounds__(256)
void prep(const int* __restrict__ src, const int* __restrict__ dst, int E, int N,
          int* cnt_in, int* cnt_out,
          const float* __restrict__ x, short* __restrict__ xb,
          const float* __restrict__ Wself, const float* __restrict__ Wstd,
          const float* __restrict__ Wdts, const float* __restrict__ Wlin,
          const float* __restrict__ bself, const float* __restrict__ bstd,
          const float* __restrict__ bdts, const float* __restrict__ alpha_p,
          short* __restrict__ wt, short* __restrict__ wlt, float* __restrict__ bcombp) {
    int b = blockIdx.x;
    if (b < CNT_BLOCKS) {
        // node-partitioned count: each group's atomics touch only its 1/8 of
        // cnt lines -> lines stay resident in one XCD's L2 (no cross-die RMW bounce)
        int xcd = b & 7, chunk = b >> 3;
        int lo = (int)((long long)xcd * N / 8);
        int hi = (int)((long long)(xcd + 1) * N / 8);
        int stride = (CNT_BLOCKS >> 3) * 256;
        for (int e = chunk * 256 + threadIdx.x; e < E; e += stride) {
            int s = src[e], d = dst[e];
            if (d >= lo && d < hi) atomicAdd(&cnt_in[d], 1);
            if (s >= lo && s < hi) atomicAdd(&cnt_out[s], 1);
        }
    } else if (b < CNT_BLOCKS + CVX_BLOCKS) {
        // x -> bf16, feature-permuted
        int total = N * 16;
        for (int i = (b - CNT_BLOCKS) * 256 + threadIdx.x; i < total; i += CVX_BLOCKS * 256) {
            int n = i >> 4, q = i & 15;
            const float* xr = x + (size_t)n * D + q;
            short8 s;
            #pragma unroll
            for (int fh = 0; fh < 8; fh++) s[fh] = (short)f2bf(xr[fh * 16]);
            *(short8*)(xb + (size_t)n * D + q * 8) = s;
        }
    } else {
        int cb = b - CNT_BLOCKS - CVX_BLOCKS;   // 0..10
        if (cb < 9) {
            int l = cb / 3, m = cb % 3;
            const float* W = (m == 0 ? Wself : (m == 1 ? Wstd : Wdts)) + (size_t)l * D * D;
            short* o = wt + (size_t)cb * D * D;
            for (int idx = threadIdx.x; idx < D * D; idx += 256) {
                int k = idx >> 7, n = idx & 127;
                o[n * D + fperm(k)] = (short)f2bf(W[idx]);
            }
        } else if (cb == 9) {
            for (int idx = threadIdx.x; idx < D * OUTD; idx += 256) {
                int k = idx >> 6, n = idx & 63;
                wlt[n * D + fperm(k)] = (short)f2bf(Wlin[idx]);
            }
        } else {
            float a = alpha_p[0];
            for (int i = threadIdx.x; i < LAYERS * D; i += 256) {
                int l = i >> 7, j = i & 127;
                bcombp[l * D + fperm(j)] = bself[i] + (1.0f - a) * bstd[i] + a * bdts[i];
            }
        }
    }
}

// ---------------- scan ----------------

__global__ __launch_bounds__(1024)
void scan2(const int* __restrict__ cnt_a, int* __restrict__ row_a,
           const int* __restrict__ cnt_b, int* __restrict__ row_b, int n) {
    const int* cnt = blockIdx.x ? cnt_b : cnt_a;
    int* row = blockIdx.x ? row_b : row_a;
    __shared__ int wsum[16];
    __shared__ int chunk_total;
    int lane = threadIdx.x & 63;
    int w = threadIdx.x >> 6;
    int carry = 0;
    int v_next = (threadIdx.x < n) ? cnt[threadIdx.x] : 0;
    for (int base = 0; base < n; base += 1024) {
        int i = base + threadIdx.x;
        int v = v_next;
        int inext = i + 1024;
        v_next = (inext < n) ? cnt[inext] : 0;
        int x = v;
        #pragma unroll
        for (int off = 1; off < 64; off <<= 1) {
            int y = __shfl_up(x, off, 64);
            if (lane >= off) x += y;
        }
        if (lane == 63) wsum[w] = x;
        __syncthreads();
        if (w == 0 && lane < 16) {
            int s = wsum[lane];
            #pragma unroll
            for (int off = 1; off < 16; off <<= 1) {
                int y = __shfl_up(s, off, 16);
                if (lane >= off) s += y;
            }
            wsum[lane] = s;
            if (lane == 15) chunk_total = s;
        }
        __syncthreads();
        int wpre = (w == 0) ? 0 : wsum[w - 1];
        if (i < n) row[i] = carry + wpre + (x - v);
        carry += chunk_total;
        __syncthreads();
    }
    if (threadIdx.x == 0) row[n] = carry;
}

// ---------------- shared GEMM body (bf16 MFMA, permuted outputs) ----------------
// z==0 -> t1b bf16 (short8 stores); z==1/2 -> t2q/t3q fp8 (uint2 stores)

__device__ __forceinline__ void gemm3_body(int mtile, int z, const short* __restrict__ Abf,
                                           int M, const short* __restrict__ wt3,
                                           short* __restrict__ t1b,
                                           uint32* __restrict__ t2q, uint32* __restrict__ t3q) {
    __shared__ __align__(16) short As[128][136];
    __shared__ __align__(16) short Bs[128][136];
    int tid = threadIdx.x;
    int m0 = mtile * 128;
    const short* Bt = wt3 + (size_t)z * D * D;

    #pragma unroll
    for (int i = 0; i < 8; i++) {
        int v = tid + i * 256;
        int row = v >> 4, c8 = v & 15;
        int gr = m0 + row;
        short8 val = {0, 0, 0, 0, 0, 0, 0, 0};
        if (gr < M) val = *(const short8*)(Abf + (size_t)gr * D + c8 * 8);
        *(short8*)&As[row][c8 * 8] = val;
    }
    #pragma unroll
    for (int i = 0; i < 8; i++) {
        int v = tid + i * 256;
        int row = v >> 4, c8 = v & 15;
        *(short8*)&Bs[row][c8 * 8] = *(const short8*)(Bt + (size_t)row * D + c8 * 8);
    }
    __syncthreads();

    int wave = tid >> 6, lane = tid & 63;
    int quad = lane >> 4, r16 = lane & 15;
    int mrow = wave * 32;

    float4v acc[2][8];
    #pragma unroll
    for (int a = 0; a < 2; a++)
        #pragma unroll
        for (int b = 0; b < 8; b++)
            acc[a][b] = (float4v){0.f, 0.f, 0.f, 0.f};

    #pragma unroll
    for (int kc = 0; kc < 4; kc++) {
        short8 a0 = *(const short8*)&As[mrow + r16][kc * 32 + quad * 8];
        short8 a1 = *(const short8*)&As[mrow + 16 + r16][kc * 32 + quad * 8];
        #pragma unroll
        for (int nt = 0; nt < 8; nt++) {
            short8 b = *(const short8*)&Bs[nt * 16 + r16][kc * 32 + quad * 8];
            acc[0][nt] = __builtin_amdgcn_mfma_f32_16x16x32_bf16(a0, b, acc[0][nt], 0, 0, 0);
            acc[1][nt] = __builtin_amdgcn_mfma_f32_16x16x32_bf16(a1, b, acc[1][nt], 0, 0, 0);
        }
    }

    // epilogue: lane holds features f = nt*16 + r16 -> permuted elements r16*8 + nt
    // (contiguous 8 elements per (rt,reg))
    #pragma unroll
    for (int rt = 0; rt < 2; rt++)
        #pragma unroll
        for (int reg = 0; reg < 4; reg++) {
            int row = m0 + mrow + rt * 16 + quad * 4 + reg;
            if (row >= M) continue;
            if (z == 0) {
                short8 s8;
                #pragma unroll
                for (int nt = 0; nt < 8; nt++) s8[nt] = (short)f2bf(acc[rt][nt][reg]);
                *(short8*)(t1b + (size_t)row * D + r16 * 8) = s8;
            } else {
                uint32 u0 = __builtin_amdgcn_cvt_pk_fp8_f32(acc[rt][0][reg], acc[rt][1][reg], 0, false);
                u0 = __builtin_amdgcn_cvt_pk_fp8_f32(acc[rt][2][reg], acc[rt][3][reg], u0, true);
                uint32 u1 = __builtin_amdgcn_cvt_pk_fp8_f32(acc[rt][4][reg], acc[rt][5][reg], 0, false);
                u1 = __builtin_amdgcn_cvt_pk_fp8_f32(acc[rt][6][reg], acc[rt][7][reg], u1, true);
                uint32* dq = ((z == 1) ? t2q : t3q) + (size_t)row * 32 + r16 * 2;
                *(uint2*)dq = make_uint2(u0, u1);
            }
        }
}

// ---------------- fused fill (XCD-local cursor atomics) + layer-0 GEMM ----------------

#define FILL_BLOCKS 1024

__global__ __launch_bounds__(256)
void fill_gemm0(const int* __restrict__ src, const int* __restrict__ dst, int E, int N,
                const int* __restrict__ row_in, const int* __restrict__ row_out,
                int* cur_in, int* cur_out,
                int* __restrict__ col_in, int* __restrict__ col_out,
                const short* __restrict__ xb, const short* __restrict__ wt,
                short* __restrict__ t1b, uint32* __restrict__ t2q, uint32* __restrict__ t3q) {
    int b = blockIdx.x;
    if (b < FILL_BLOCKS) {
        int xcd = b & 7, chunk = b >> 3;
        int lo = (int)((long long)xcd * N / 8);
        int hi = (int)((long long)(xcd + 1) * N / 8);
        int stride = (FILL_BLOCKS >> 3) * 256;
        for (int e = chunk * 256 + threadIdx.x; e < E; e += stride) {
            int s = src[e], d = dst[e];
            if (d >= lo && d < hi) { int p = atomicAdd(&cur_in[d], 1);  col_in[row_in[d] + p] = s; }
            if (s >= lo && s < hi) { int q = atomicAdd(&cur_out[s], 1); col_out[row_out[s] + q] = d; }
        }
    } else {
        int g = b - FILL_BLOCKS;
        gemm3_body(g / 3, g % 3, xb, N, wt, t1b, t2q, t3q);
    }
}

__global__ __launch_bounds__(256)
void gemm3_k(const short* __restrict__ hin, int M, const short* __restrict__ wt3,
             short* __restrict__ t1b, uint32* __restrict__ t2q, uint32* __restrict__ t3q) {
    gemm3_body(blockIdx.x, blockIdx.z, hin, M, wt3, t1b, t2q, t3q);
}

// ---------------- Final GEMM (MFMA): out = jkb(bf16, permuted-k) @ wlt^T + blin ----------------

__global__ __launch_bounds__(256)
void gemm_out_mfma(const short* __restrict__ jkb, int M, const short* __restrict__ wlt,
                   const float* __restrict__ blin, float* __restrict__ Cout) {
    __shared__ __align__(16) short As[128][136];
    __shared__ __align__(16) short Bs[64][136];
    int tid = threadIdx.x;
    int m0 = blockIdx.x * 128;

    #pragma unroll
    for (int i = 0; i < 8; i++) {
        int v = tid + i * 256;
        int row = v >> 4, c8 = v & 15;
        int gr = m0 + row;
        short8 val = {0, 0, 0, 0, 0, 0, 0, 0};
        if (gr < M) val = *(const short8*)(jkb + (size_t)gr * D + c8 * 8);
        *(short8*)&As[row][c8 * 8] = val;
    }
    #pragma unroll
    for (int i = 0; i < 4; i++) {
        int v = tid + i * 256;
        int row = v >> 4, c8 = v & 15;
        *(short8*)&Bs[row][c8 * 8] = *(const short8*)(wlt + (size_t)row * D + c8 * 8);
    }
    __syncthreads();

    int wave = tid >> 6, lane = tid & 63;
    int quad = lane >> 4, r16 = lane & 15;
    int mrow = wave * 32;

    float4v acc[2][4];
    #pragma unroll
    for (int a = 0; a < 2; a++)
        #pragma unroll
        for (int b = 0; b < 4; b++)
            acc[a][b] = (float4v){0.f, 0.f, 0.f, 0.f};

    #pragma unroll
    for (int kc = 0; kc < 4; kc++) {
        short8 a0 = *(const short8*)&As[mrow + r16][kc * 32 + quad * 8];
        short8 a1 = *(const short8*)&As[mrow + 16 + r16][kc * 32 + quad * 8];
        #pragma unroll
        for (int nt = 0; nt < 4; nt++) {
            short8 b = *(const short8*)&Bs[nt * 16 + r16][kc * 32 + quad * 8];
            acc[0][nt] = __builtin_amdgcn_mfma_f32_16x16x32_bf16(a0, b, acc[0][nt], 0, 0, 0);
            acc[1][nt] = __builtin_amdgcn_mfma_f32_16x16x32_bf16(a1, b, acc[1][nt], 0, 0, 0);
        }
    }

    #pragma unroll
    for (int rt = 0; rt < 2; rt++)
        #pragma unroll
        for (int nt = 0; nt < 4; nt++)
            #pragma unroll
            for (int reg = 0; reg < 4; reg++) {
                int row = m0 + mrow + rt * 16 + quad * 4 + reg;
                int col = nt * 16 + r16;
                if (row < M) Cout[(size_t)row * OUTD + col] = acc[rt][nt][reg] + blin[col];
            }
}

// ---------------- Fused aggregation: fp8 gathers, 2 rows/load, dual-stream ----------------
// One wave per node; fp8 rows are 128 B -> lanes 0-31 cover row u0, lanes 32-63
// row u1 (readlane pair select). HW cvt_pk_f32_fp8 decode, float2 accumulate,
// cross-half shfl_xor reduce, epilogue on lanes 0-31 (4 permuted elements each).

__global__ __launch_bounds__(256)
void agg_epilogue(const short* __restrict__ t1b,
                  const uint32* __restrict__ t2q, const uint32* __restrict__ t3q,
                  const float* __restrict__ bcombp,
                  const int* __restrict__ row_in, const int* __restrict__ col_in,
                  const int* __restrict__ row_out, const int* __restrict__ col_out,
                  const float* __restrict__ alpha_p,
                  short* __restrict__ h_out, short* __restrict__ jkb,
                  int first, int N) {
    int wv = threadIdx.x >> 6;
    int lane = threadIdx.x & 63;
    int n = blockIdx.x * 4 + wv;
    if (n >= N) return;
    float a = alpha_p[0];
    int s_in = row_in[n], e_in = row_in[n + 1];
    int s_out = row_out[n], e_out = row_out[n + 1];
    int din = e_in - s_in, dout = e_out - s_out;
    bool lower = lane < 32;
    uint32 off32 = lane & 31;

    floatx2 ai0 = {0.f, 0.f}, ai1 = {0.f, 0.f};
    floatx2 ao0 = {0.f, 0.f}, ao1 = {0.f, 0.f};

    int pin = s_in, pout = s_out;
    while (pin < e_in || pout < e_out) {
        int m_in = e_in - pin;   if (m_in > 64) m_in = 64;   if (m_in < 0) m_in = 0;
        int m_out = e_out - pout; if (m_out > 64) m_out = 64; if (m_out < 0) m_out = 0;
        int idxi = (lane < m_in) ? col_in[pin + lane] : 0;
        int idxo = (lane < m_out) ? col_out[pout + lane] : 0;
        int fi = m_in & ~15, fo = m_out & ~15;
        int ji = 0, jo = 0;
        while (ji < fi || jo < fo) {
            uint32 wi[8], wo[8];
            bool di = ji < fi, dw = jo < fo;
            if (di) {
                #pragma unroll
                for (int t = 0; t < 8; t++) {
                    int u0 = __builtin_amdgcn_readlane(idxi, ji + 2 * t);
                    int u1 = __builtin_amdgcn_readlane(idxi, ji + 2 * t + 1);
                    int us = lower ? u0 : u1;
                    wi[t] = t2q[(size_t)us * 32 + off32];
                }
            }
            if (dw) {
                #pragma unroll
                for (int t = 0; t < 8; t++) {
                    int u0 = __builtin_amdgcn_readlane(idxo, jo + 2 * t);
                    int u1 = __builtin_amdgcn_readlane(idxo, jo + 2 * t + 1);
                    int us = lower ? u0 : u1;
                    wo[t] = t3q[(size_t)us * 32 + off32];
                }
            }
            if (di) {
                #pragma unroll
                for (int t = 0; t < 8; t++) {
                    ai0 += __builtin_amdgcn_cvt_pk_f32_fp8(wi[t], false);
                    ai1 += __builtin_amdgcn_cvt_pk_f32_fp8(wi[t], true);
                }
                ji += 16;
            }
            if (dw) {
                #pragma unroll
                for (int t = 0; t < 8; t++) {
                    ao0 += __builtin_amdgcn_cvt_pk_f32_fp8(wo[t], false);
                    ao1 += __builtin_amdgcn_cvt_pk_f32_fp8(wo[t], true);
                }
                jo += 16;
            }
        }
        int ri = m_in - fi, ro = m_out - fo;   // 0..15 remaining rows per stream
        if (ri | ro) {
            uint32 wi[8], wo[8];
            #pragma unroll
            for (int t = 0; t < 8; t++) { wi[t] = 0u; wo[t] = 0u; }
            #pragma unroll
            for (int t = 0; t < 8; t++) {
                if (2 * t < ri) {
                    int j0 = fi + 2 * t;
                    int j1 = (2 * t + 1 < ri) ? j0 + 1 : j0;
                    int u0 = __builtin_amdgcn_readlane(idxi, j0);
                    int u1 = __builtin_amdgcn_readlane(idxi, j1);
                    int us = lower ? u0 : u1;
                    uint32 v = t2q[(size_t)us * 32 + off32];
                    if (2 * t + 1 >= ri) v = lower ? v : 0u;
                    wi[t] = v;
                }
            }
            #pragma unroll
            for (int t = 0; t < 8; t++) {
                if (2 * t < ro) {
                    int j0 = fo + 2 * t;
                    int j1 = (2 * t + 1 < ro) ? j0 + 1 : j0;
                    int u0 = __builtin_amdgcn_readlane(idxo, j0);
                    int u1 = __builtin_amdgcn_readlane(idxo, j1);
                    int us = lower ? u0 : u1;
                    uint32 v = t3q[(size_t)us * 32 + off32];
                    if (2 * t + 1 >= ro) v = lower ? v : 0u;
                    wo[t] = v;
                }
            }
            #pragma unroll
            for (int t = 0; t < 8; t++) {
                ai0 += __builtin_amdgcn_cvt_pk_f32_fp8(wi[t], false);
                ai1 += __builtin_amdgcn_cvt_pk_f32_fp8(wi[t], true);
                ao0 += __builtin_amdgcn_cvt_pk_f32_fp8(wo[t], false);
                ao1 += __builtin_amdgcn_cvt_pk_f32_fp8(wo[t], true);
            }
        }
        pin += m_in; pout += m_out;
    }

    // lanes L and L^32 accumulated the same 4 elements over different rows
    ai0.x += __shfl_xor(ai0.x, 32, 64); ai0.y += __shfl_xor(ai0.y, 32, 64);
    ai1.x += __shfl_xor(ai1.x, 32, 64); ai1.y += __shfl_xor(ai1.y, 32, 64);
    ao0.x += __shfl_xor(ao0.x, 32, 64); ao0.y += __shfl_xor(ao0.y, 32, 64);
    ao1.x += __shfl_xor(ao1.x, 32, 64); ao1.y += __shfl_xor(ao1.y, 32, 64);

    if (lower) {
        float win = (1.0f - a) / (float)max(din, 1);
        float wout = a / (float)max(dout, 1);
        int L = lane;   // 0..31 -> permuted elements 4L..4L+3
        uint2 tv = *(const uint2*)(t1b + (size_t)n * D + 4 * L);
        float4 bc = *(const float4*)(bcombp + 4 * L);
        float t0 = __uint_as_float(tv.x << 16);
        float t1 = __uint_as_float(tv.x & 0xFFFF0000u);
        float t2 = __uint_as_float(tv.y << 16);
        float t3 = __uint_as_float(tv.y & 0xFFFF0000u);
        float h0 = fmaxf(t0 + bc.x + win * ai0.x + wout * ao0.x, 0.f);
        float h1 = fmaxf(t1 + bc.y + win * ai0.y + wout * ao0.y, 0.f);
        float h2 = fmaxf(t2 + bc.z + win * ai1.x + wout * ao1.x, 0.f);
        float h3 = fmaxf(t3 + bc.w + win * ai1.y + wout * ao1.y, 0.f);
        uint32 p0 = (uint32)f2bf(h0) | ((uint32)f2bf(h1) << 16);
        uint32 p1 = (uint32)f2bf(h2) | ((uint32)f2bf(h3) << 16);
        if (h_out) *(uint2*)(h_out + (size_t)n * D + 4 * L) = make_uint2(p0, p1);
        uint2* jp = (uint2*)(jkb + (size_t)n * D + 4 * L);
        if (first) {
            *jp = make_uint2(p0, p1);
        } else {
            // relu'd bf16 >= 0 -> monotone as u16; per-half max
            uint2 old = *jp;
            uint32 q0 = max(old.x & 0xFFFFu, p0 & 0xFFFFu) | max(old.x & 0xFFFF0000u, p0 & 0xFFFF0000u);
            uint32 q1 = max(old.y & 0xFFFFu, p1 & 0xFFFFu) | max(old.y & 0xFFFF0000u, p1 & 0xFFFF0000u);
            *jp = make_uint2(q0, q1);
        }
    }
}

// ---------------- launch ----------------

extern "C" void kernel_launch(void* const* d_in, const int* in_sizes, int n_in,
                              void* d_out, int out_size, void* d_ws, size_t ws_size,
                              hipStream_t stream) {
    const float* x     = (const float*)d_in[0];
    const int*   ei    = (const int*)d_in[1];
    const float* Wself = (const float*)d_in[2];
    const float* bself = (const float*)d_in[3];
    const float* Wstd  = (const float*)d_in[4];
    const float* bstd  = (const float*)d_in[5];
    const float* Wdts  = (const float*)d_in[6];
    const float* bdts  = (const float*)d_in[7];
    const float* Wlin  = (const float*)d_in[8];
    const float* blin  = (const float*)d_in[9];
    const float* alpha = (const float*)d_in[10];

    int N = in_sizes[0] / D;   // 50000
    int E = in_sizes[1] / 2;   // 800000

    char* p = (char*)d_ws;
    auto alloc = [&](size_t bytes) {
        char* q = p;
        p += (bytes + 255) & ~(size_t)255;
        return q;
    };
    int* cnt_in  = (int*)alloc((size_t)N * 4);
    int* cnt_out = (int*)alloc((size_t)N * 4);
    int* cur_in  = (int*)alloc((size_t)N * 4);
    int* cur_out = (int*)alloc((size_t)N * 4);
    int* row_in  = (int*)alloc((size_t)(N + 1) * 4);
    int* row_out = (int*)alloc((size_t)(N + 1) * 4);
    int* col_in  = (int*)alloc((size_t)E * 4);
    int* col_out = (int*)alloc((size_t)E * 4);
    short* xb    = (short*)alloc((size_t)N * D * 2);
    short* hb    = (short*)alloc((size_t)N * D * 2);
    short* wt    = (short*)alloc((size_t)9 * D * D * 2);
    short* wlt   = (short*)alloc((size_t)D * OUTD * 2);
    float* bcombp = (float*)alloc((size_t)LAYERS * D * 4);
    short* t1b   = (short*)alloc((size_t)N * D * 2);
    uint32* t2q  = (uint32*)alloc((size_t)N * 32 * 4);   // fp8, 128 B/row
    uint32* t3q  = (uint32*)alloc((size_t)N * 32 * 4);
    short* jkb   = (short*)alloc((size_t)N * D * 2);

    const int* srcp = ei;
    const int* dstp = ei + E;

    hipMemsetAsync(cnt_in, 0, (size_t)N * 4, stream);
    hipMemsetAsync(cnt_out, 0, (size_t)N * 4, stream);
    hipMemsetAsync(cur_in, 0, (size_t)N * 4, stream);
    hipMemsetAsync(cur_out, 0, (size_t)N * 4, stream);

    prep<<<CNT_BLOCKS + CVX_BLOCKS + 11, 256, 0, stream>>>(
        srcp, dstp, E, N, cnt_in, cnt_out, x, xb,
        Wself, Wstd, Wdts, Wlin, bself, bstd, bdts, alpha, wt, wlt, bcombp);
    scan2<<<2, 1024, 0, stream>>>(cnt_in, row_in, cnt_out, row_out, N);

    int gm = ceil_div(N, 128);
    fill_gemm0<<<FILL_BLOCKS + 3 * gm, 256, 0, stream>>>(
        srcp, dstp, E, N, row_in, row_out, cur_in, cur_out, col_in, col_out,
        xb, wt, t1b, t2q, t3q);

    for (int l = 0; l < LAYERS; l++) {
        agg_epilogue<<<ceil_div(N, 4), 256, 0, stream>>>(
            t1b, t2q, t3q, bcombp + (size_t)l * D,
            row_in, col_in, row_out, col_out, alpha,
            (l == LAYERS - 1) ? nullptr : hb, jkb, (l == 0) ? 1 : 0, N);
        if (l < LAYERS - 1)
            gemm3_k<<<dim3(gm, 1, 3), 256, 0, stream>>>(hb, N, wt + (size_t)(l + 1) * 3 * D * D,
                                                        t1b, t2q, t3q);
    }
    gemm_out_mfma<<<gm, 256, 0, stream>>>(jkb, N, wlt, blin, (float*)d_out);
}

// Round 7
// 510.945 us; speedup vs baseline: 1.0299x; 1.0299x over previous
//
#include <hip/hip_runtime.h>

#define D 128
#define OUTD 64
#define LAYERS 3

typedef __attribute__((ext_vector_type(8))) short short8;
typedef __attribute__((ext_vector_type(4))) float float4v;
typedef __attribute__((ext_vector_type(2))) float floatx2;
typedef unsigned int uint32;

static inline int ceil_div(int a, int b) { return (a + b - 1) / b; }

__device__ __forceinline__ unsigned short f2bf(float f) {
    unsigned int u = __float_as_uint(f);
    unsigned int r = u + 0x7FFFu + ((u >> 16) & 1u);
    return (unsigned short)(r >> 16);
}

// feature permutation: storage element position of logical feature f.
// Applied identically to all k-dim storages -> GEMM dot products unchanged,
// epilogue stores become lane-contiguous.
__device__ __forceinline__ int fperm(int f) { return (f & 15) * 8 + (f >> 4); }

// ---------------- prep: XCD-partitioned degree count + all converts ----------------

#define CNT_BLOCKS 1280   // 8 node-range groups x 160 blocks
#define CVX_BLOCKS 1044

__global__ __launch_bounds__(256)
void prep(const int* __restrict__ src, const int* __restrict__ dst, int E, int N,
          int* cnt_in, int* cnt_out,
          const float* __restrict__ x, short* __restrict__ xb,
          const float* __restrict__ Wself, const float* __restrict__ Wstd,
          const float* __restrict__ Wdts, const float* __restrict__ Wlin,
          const float* __restrict__ bself, const float* __restrict__ bstd,
          const float* __restrict__ bdts, const float* __restrict__ alpha_p,
          short* __restrict__ wt, short* __restrict__ wlt, float* __restrict__ bcombp) {
    int b = blockIdx.x;
    if (b < CNT_BLOCKS) {
        int xcd = b & 7, chunk = b >> 3;
        int lo = (int)((long long)xcd * N / 8);
        int hi = (int)((long long)(xcd + 1) * N / 8);
        int stride = (CNT_BLOCKS >> 3) * 256;
        for (int e = chunk * 256 + threadIdx.x; e < E; e += stride) {
            int s = src[e], d = dst[e];
            if (d >= lo && d < hi) atomicAdd(&cnt_in[d], 1);
            if (s >= lo && s < hi) atomicAdd(&cnt_out[s], 1);
        }
    } else if (b < CNT_BLOCKS + CVX_BLOCKS) {
        int total = N * 16;
        for (int i = (b - CNT_BLOCKS) * 256 + threadIdx.x; i < total; i += CVX_BLOCKS * 256) {
            int n = i >> 4, q = i & 15;
            const float* xr = x + (size_t)n * D + q;
            short8 s;
            #pragma unroll
            for (int fh = 0; fh < 8; fh++) s[fh] = (short)f2bf(xr[fh * 16]);
            *(short8*)(xb + (size_t)n * D + q * 8) = s;
        }
    } else {
        int cb = b - CNT_BLOCKS - CVX_BLOCKS;   // 0..10
        if (cb < 9) {
            int l = cb / 3, m = cb % 3;
            const float* W = (m == 0 ? Wself : (m == 1 ? Wstd : Wdts)) + (size_t)l * D * D;
            short* o = wt + (size_t)cb * D * D;
            for (int idx = threadIdx.x; idx < D * D; idx += 256) {
                int k = idx >> 7, n = idx & 127;
                o[n * D + fperm(k)] = (short)f2bf(W[idx]);
            }
        } else if (cb == 9) {
            for (int idx = threadIdx.x; idx < D * OUTD; idx += 256) {
                int k = idx >> 6, n = idx & 63;
                wlt[n * D + fperm(k)] = (short)f2bf(Wlin[idx]);
            }
        } else {
            float a = alpha_p[0];
            for (int i = threadIdx.x; i < LAYERS * D; i += 256) {
                int l = i >> 7, j = i & 127;
                bcombp[l * D + fperm(j)] = bself[i] + (1.0f - a) * bstd[i] + a * bdts[i];
            }
        }
    }
}

// ---------------- scan ----------------

__global__ __launch_bounds__(1024)
void scan2(const int* __restrict__ cnt_a, int* __restrict__ row_a,
           const int* __restrict__ cnt_b, int* __restrict__ row_b, int n) {
    const int* cnt = blockIdx.x ? cnt_b : cnt_a;
    int* row = blockIdx.x ? row_b : row_a;
    __shared__ int wsum[16];
    __shared__ int chunk_total;
    int lane = threadIdx.x & 63;
    int w = threadIdx.x >> 6;
    int carry = 0;
    int v_next = (threadIdx.x < n) ? cnt[threadIdx.x] : 0;
    for (int base = 0; base < n; base += 1024) {
        int i = base + threadIdx.x;
        int v = v_next;
        int inext = i + 1024;
        v_next = (inext < n) ? cnt[inext] : 0;
        int x = v;
        #pragma unroll
        for (int off = 1; off < 64; off <<= 1) {
            int y = __shfl_up(x, off, 64);
            if (lane >= off) x += y;
        }
        if (lane == 63) wsum[w] = x;
        __syncthreads();
        if (w == 0 && lane < 16) {
            int s = wsum[lane];
            #pragma unroll
            for (int off = 1; off < 16; off <<= 1) {
                int y = __shfl_up(s, off, 16);
                if (lane >= off) s += y;
            }
            wsum[lane] = s;
            if (lane == 15) chunk_total = s;
        }
        __syncthreads();
        int wpre = (w == 0) ? 0 : wsum[w - 1];
        if (i < n) row[i] = carry + wpre + (x - v);
        carry += chunk_total;
        __syncthreads();
    }
    if (threadIdx.x == 0) row[n] = carry;
}

// ---------------- slim GEMM body: A direct from global, only B staged in LDS ----------------
// LDS = 128x136 shorts = 34.8 KB -> 4 blocks/CU (vs 2 with As staged).
// A fragments are lane-contiguous 16B chunks read once per block -> no LDS needed.
// z==0 -> t1b bf16 (short8 stores); z==1/2 -> t2q/t3q fp8 (uint2 stores)

__device__ __forceinline__ void gemm3_body(int mtile, int z, const short* __restrict__ Abf,
                                           int M, const short* __restrict__ wt3,
                                           short* __restrict__ t1b,
                                           uint32* __restrict__ t2q, uint32* __restrict__ t3q) {
    __shared__ __align__(16) short Bs[128][136];
    int tid = threadIdx.x;
    int m0 = mtile * 128;
    const short* Bt = wt3 + (size_t)z * D * D;

    #pragma unroll
    for (int i = 0; i < 8; i++) {
        int v = tid + i * 256;
        int row = v >> 4, c8 = v & 15;
        *(short8*)&Bs[row][c8 * 8] = *(const short8*)(Bt + (size_t)row * D + c8 * 8);
    }
    __syncthreads();

    int wave = tid >> 6, lane = tid & 63;
    int quad = lane >> 4, r16 = lane & 15;
    int mrow = wave * 32;
    int gr0 = m0 + mrow + r16;
    int gr1 = gr0 + 16;

    float4v acc[2][8];
    #pragma unroll
    for (int a = 0; a < 2; a++)
        #pragma unroll
        for (int b = 0; b < 8; b++)
            acc[a][b] = (float4v){0.f, 0.f, 0.f, 0.f};

    #pragma unroll
    for (int kc = 0; kc < 4; kc++) {
        short8 a0 = {0, 0, 0, 0, 0, 0, 0, 0};
        short8 a1 = {0, 0, 0, 0, 0, 0, 0, 0};
        if (gr0 < M) a0 = *(const short8*)(Abf + (size_t)gr0 * D + kc * 32 + quad * 8);
        if (gr1 < M) a1 = *(const short8*)(Abf + (size_t)gr1 * D + kc * 32 + quad * 8);
        #pragma unroll
        for (int nt = 0; nt < 8; nt++) {
            short8 b = *(const short8*)&Bs[nt * 16 + r16][kc * 32 + quad * 8];
            acc[0][nt] = __builtin_amdgcn_mfma_f32_16x16x32_bf16(a0, b, acc[0][nt], 0, 0, 0);
            acc[1][nt] = __builtin_amdgcn_mfma_f32_16x16x32_bf16(a1, b, acc[1][nt], 0, 0, 0);
        }
    }

    // epilogue: lane holds features f = nt*16 + r16 -> permuted elements r16*8 + nt
    #pragma unroll
    for (int rt = 0; rt < 2; rt++)
        #pragma unroll
        for (int reg = 0; reg < 4; reg++) {
            int row = m0 + mrow + rt * 16 + quad * 4 + reg;
            if (row >= M) continue;
            if (z == 0) {
                short8 s8;
                #pragma unroll
                for (int nt = 0; nt < 8; nt++) s8[nt] = (short)f2bf(acc[rt][nt][reg]);
                *(short8*)(t1b + (size_t)row * D + r16 * 8) = s8;
            } else {
                uint32 u0 = __builtin_amdgcn_cvt_pk_fp8_f32(acc[rt][0][reg], acc[rt][1][reg], 0, false);
                u0 = __builtin_amdgcn_cvt_pk_fp8_f32(acc[rt][2][reg], acc[rt][3][reg], u0, true);
                uint32 u1 = __builtin_amdgcn_cvt_pk_fp8_f32(acc[rt][4][reg], acc[rt][5][reg], 0, false);
                u1 = __builtin_amdgcn_cvt_pk_fp8_f32(acc[rt][6][reg], acc[rt][7][reg], u1, true);
                uint32* dq = ((z == 1) ? t2q : t3q) + (size_t)row * 32 + r16 * 2;
                *(uint2*)dq = make_uint2(u0, u1);
            }
        }
}

// ---------------- fused fill (XCD-local cursor atomics) + layer-0 GEMM ----------------

#define FILL_BLOCKS 1024

__global__ __launch_bounds__(256)
void fill_gemm0(const int* __restrict__ src, const int* __restrict__ dst, int E, int N,
                const int* __restrict__ row_in, const int* __restrict__ row_out,
                int* cur_in, int* cur_out,
                int* __restrict__ col_in, int* __restrict__ col_out,
                const short* __restrict__ xb, const short* __restrict__ wt,
                short* __restrict__ t1b, uint32* __restrict__ t2q, uint32* __restrict__ t3q) {
    int b = blockIdx.x;
    if (b < FILL_BLOCKS) {
        int xcd = b & 7, chunk = b >> 3;
        int lo = (int)((long long)xcd * N / 8);
        int hi = (int)((long long)(xcd + 1) * N / 8);
        int stride = (FILL_BLOCKS >> 3) * 256;
        for (int e = chunk * 256 + threadIdx.x; e < E; e += stride) {
            int s = src[e], d = dst[e];
            if (d >= lo && d < hi) { int p = atomicAdd(&cur_in[d], 1);  col_in[row_in[d] + p] = s; }
            if (s >= lo && s < hi) { int q = atomicAdd(&cur_out[s], 1); col_out[row_out[s] + q] = d; }
        }
    } else {
        int g = b - FILL_BLOCKS;
        gemm3_body(g / 3, g % 3, xb, N, wt, t1b, t2q, t3q);
    }
}

__global__ __launch_bounds__(256)
void gemm3_k(const short* __restrict__ hin, int M, const short* __restrict__ wt3,
             short* __restrict__ t1b, uint32* __restrict__ t2q, uint32* __restrict__ t3q) {
    gemm3_body(blockIdx.x, blockIdx.z, hin, M, wt3, t1b, t2q, t3q);
}

// ---------------- Final GEMM (MFMA, slim): out = jkb(bf16, permuted-k) @ wlt^T + blin ----------------

__global__ __launch_bounds__(256)
void gemm_out_mfma(const short* __restrict__ jkb, int M, const short* __restrict__ wlt,
                   const float* __restrict__ blin, float* __restrict__ Cout) {
    __shared__ __align__(16) short Bs[64][136];
    int tid = threadIdx.x;
    int m0 = blockIdx.x * 128;

    #pragma unroll
    for (int i = 0; i < 4; i++) {
        int v = tid + i * 256;
        int row = v >> 4, c8 = v & 15;
        *(short8*)&Bs[row][c8 * 8] = *(const short8*)(wlt + (size_t)row * D + c8 * 8);
    }
    __syncthreads();

    int wave = tid >> 6, lane = tid & 63;
    int quad = lane >> 4, r16 = lane & 15;
    int mrow = wave * 32;
    int gr0 = m0 + mrow + r16;
    int gr1 = gr0 + 16;

    float4v acc[2][4];
    #pragma unroll
    for (int a = 0; a < 2; a++)
        #pragma unroll
        for (int b = 0; b < 4; b++)
            acc[a][b] = (float4v){0.f, 0.f, 0.f, 0.f};

    #pragma unroll
    for (int kc = 0; kc < 4; kc++) {
        short8 a0 = {0, 0, 0, 0, 0, 0, 0, 0};
        short8 a1 = {0, 0, 0, 0, 0, 0, 0, 0};
        if (gr0 < M) a0 = *(const short8*)(jkb + (size_t)gr0 * D + kc * 32 + quad * 8);
        if (gr1 < M) a1 = *(const short8*)(jkb + (size_t)gr1 * D + kc * 32 + quad * 8);
        #pragma unroll
        for (int nt = 0; nt < 4; nt++) {
            short8 b = *(const short8*)&Bs[nt * 16 + r16][kc * 32 + quad * 8];
            acc[0][nt] = __builtin_amdgcn_mfma_f32_16x16x32_bf16(a0, b, acc[0][nt], 0, 0, 0);
            acc[1][nt] = __builtin_amdgcn_mfma_f32_16x16x32_bf16(a1, b, acc[1][nt], 0, 0, 0);
        }
    }

    #pragma unroll
    for (int rt = 0; rt < 2; rt++)
        #pragma unroll
        for (int nt = 0; nt < 4; nt++)
            #pragma unroll
            for (int reg = 0; reg < 4; reg++) {
                int row = m0 + mrow + rt * 16 + quad * 4 + reg;
                int col = nt * 16 + r16;
                if (row < M) Cout[(size_t)row * OUTD + col] = acc[rt][nt][reg] + blin[col];
            }
}

// ---------------- Fused aggregation: fp8 gathers, 2 rows/load, dual-stream ----------------

__global__ __launch_bounds__(256)
void agg_epilogue(const short* __restrict__ t1b,
                  const uint32* __restrict__ t2q, const uint32* __restrict__ t3q,
                  const float* __restrict__ bcombp,
                  const int* __restrict__ row_in, const int* __restrict__ col_in,
                  const int* __restrict__ row_out, const int* __restrict__ col_out,
                  const float* __restrict__ alpha_p,
                  short* __restrict__ h_out, short* __restrict__ jkb,
                  int first, int N) {
    int wv = threadIdx.x >> 6;
    int lane = threadIdx.x & 63;
    int n = blockIdx.x * 4 + wv;
    if (n >= N) return;
    float a = alpha_p[0];
    int s_in = row_in[n], e_in = row_in[n + 1];
    int s_out = row_out[n], e_out = row_out[n + 1];
    int din = e_in - s_in, dout = e_out - s_out;
    bool lower = lane < 32;
    uint32 off32 = lane & 31;

    floatx2 ai0 = {0.f, 0.f}, ai1 = {0.f, 0.f};
    floatx2 ao0 = {0.f, 0.f}, ao1 = {0.f, 0.f};

    int pin = s_in, pout = s_out;
    while (pin < e_in || pout < e_out) {
        int m_in = e_in - pin;   if (m_in > 64) m_in = 64;   if (m_in < 0) m_in = 0;
        int m_out = e_out - pout; if (m_out > 64) m_out = 64; if (m_out < 0) m_out = 0;
        int idxi = (lane < m_in) ? col_in[pin + lane] : 0;
        int idxo = (lane < m_out) ? col_out[pout + lane] : 0;
        int fi = m_in & ~15, fo = m_out & ~15;
        int ji = 0, jo = 0;
        while (ji < fi || jo < fo) {
            uint32 wi[8], wo[8];
            bool di = ji < fi, dw = jo < fo;
            if (di) {
                #pragma unroll
                for (int t = 0; t < 8; t++) {
                    int u0 = __builtin_amdgcn_readlane(idxi, ji + 2 * t);
                    int u1 = __builtin_amdgcn_readlane(idxi, ji + 2 * t + 1);
                    int us = lower ? u0 : u1;
                    wi[t] = t2q[(size_t)us * 32 + off32];
                }
            }
            if (dw) {
                #pragma unroll
                for (int t = 0; t < 8; t++) {
                    int u0 = __builtin_amdgcn_readlane(idxo, jo + 2 * t);
                    int u1 = __builtin_amdgcn_readlane(idxo, jo + 2 * t + 1);
                    int us = lower ? u0 : u1;
                    wo[t] = t3q[(size_t)us * 32 + off32];
                }
            }
            if (di) {
                #pragma unroll
                for (int t = 0; t < 8; t++) {
                    ai0 += __builtin_amdgcn_cvt_pk_f32_fp8(wi[t], false);
                    ai1 += __builtin_amdgcn_cvt_pk_f32_fp8(wi[t], true);
                }
                ji += 16;
            }
            if (dw) {
                #pragma unroll
                for (int t = 0; t < 8; t++) {
                    ao0 += __builtin_amdgcn_cvt_pk_f32_fp8(wo[t], false);
                    ao1 += __builtin_amdgcn_cvt_pk_f32_fp8(wo[t], true);
                }
                jo += 16;
            }
        }
        int ri = m_in - fi, ro = m_out - fo;   // 0..15
        if (ri | ro) {
            uint32 wi[8], wo[8];
            #pragma unroll
            for (int t = 0; t < 8; t++) { wi[t] = 0u; wo[t] = 0u; }
            #pragma unroll
            for (int t = 0; t < 8; t++) {
                if (2 * t < ri) {
                    int j0 = fi + 2 * t;
                    int j1 = (2 * t + 1 < ri) ? j0 + 1 : j0;
                    int u0 = __builtin_amdgcn_readlane(idxi, j0);
                    int u1 = __builtin_amdgcn_readlane(idxi, j1);
                    int us = lower ? u0 : u1;
                    uint32 v = t2q[(size_t)us * 32 + off32];
                    if (2 * t + 1 >= ri) v = lower ? v : 0u;
                    wi[t] = v;
                }
            }
            #pragma unroll
            for (int t = 0; t < 8; t++) {
                if (2 * t < ro) {
                    int j0 = fo + 2 * t;
                    int j1 = (2 * t + 1 < ro) ? j0 + 1 : j0;
                    int u0 = __builtin_amdgcn_readlane(idxo, j0);
                    int u1 = __builtin_amdgcn_readlane(idxo, j1);
                    int us = lower ? u0 : u1;
                    uint32 v = t3q[(size_t)us * 32 + off32];
                    if (2 * t + 1 >= ro) v = lower ? v : 0u;
                    wo[t] = v;
                }
            }
            #pragma unroll
            for (int t = 0; t < 8; t++) {
                ai0 += __builtin_amdgcn_cvt_pk_f32_fp8(wi[t], false);
                ai1 += __builtin_amdgcn_cvt_pk_f32_fp8(wi[t], true);
                ao0 += __builtin_amdgcn_cvt_pk_f32_fp8(wo[t], false);
                ao1 += __builtin_amdgcn_cvt_pk_f32_fp8(wo[t], true);
            }
        }
        pin += m_in; pout += m_out;
    }

    ai0.x += __shfl_xor(ai0.x, 32, 64); ai0.y += __shfl_xor(ai0.y, 32, 64);
    ai1.x += __shfl_xor(ai1.x, 32, 64); ai1.y += __shfl_xor(ai1.y, 32, 64);
    ao0.x += __shfl_xor(ao0.x, 32, 64); ao0.y += __shfl_xor(ao0.y, 32, 64);
    ao1.x += __shfl_xor(ao1.x, 32, 64); ao1.y += __shfl_xor(ao1.y, 32, 64);

    if (lower) {
        float win = (1.0f - a) / (float)max(din, 1);
        float wout = a / (float)max(dout, 1);
        int L = lane;   // 0..31 -> permuted elements 4L..4L+3
        uint2 tv = *(const uint2*)(t1b + (size_t)n * D + 4 * L);
        float4 bc = *(const float4*)(bcombp + 4 * L);
        float t0 = __uint_as_float(tv.x << 16);
        float t1 = __uint_as_float(tv.x & 0xFFFF0000u);
        float t2 = __uint_as_float(tv.y << 16);
        float t3 = __uint_as_float(tv.y & 0xFFFF0000u);
        float h0 = fmaxf(t0 + bc.x + win * ai0.x + wout * ao0.x, 0.f);
        float h1 = fmaxf(t1 + bc.y + win * ai0.y + wout * ao0.y, 0.f);
        float h2 = fmaxf(t2 + bc.z + win * ai1.x + wout * ao1.x, 0.f);
        float h3 = fmaxf(t3 + bc.w + win * ai1.y + wout * ao1.y, 0.f);
        uint32 p0 = (uint32)f2bf(h0) | ((uint32)f2bf(h1) << 16);
        uint32 p1 = (uint32)f2bf(h2) | ((uint32)f2bf(h3) << 16);
        if (h_out) *(uint2*)(h_out + (size_t)n * D + 4 * L) = make_uint2(p0, p1);
        uint2* jp = (uint2*)(jkb + (size_t)n * D + 4 * L);
        if (first) {
            *jp = make_uint2(p0, p1);
        } else {
            uint2 old = *jp;
            uint32 q0 = max(old.x & 0xFFFFu, p0 & 0xFFFFu) | max(old.x & 0xFFFF0000u, p0 & 0xFFFF0000u);
            uint32 q1 = max(old.y & 0xFFFFu, p1 & 0xFFFFu) | max(old.y & 0xFFFF0000u, p1 & 0xFFFF0000u);
            *jp = make_uint2(q0, q1);
        }
    }
}

// ---------------- launch ----------------

extern "C" void kernel_launch(void* const* d_in, const int* in_sizes, int n_in,
                              void* d_out, int out_size, void* d_ws, size_t ws_size,
                              hipStream_t stream) {
    const float* x     = (const float*)d_in[0];
    const int*   ei    = (const int*)d_in[1];
    const float* Wself = (const float*)d_in[2];
    const float* bself = (const float*)d_in[3];
    const float* Wstd  = (const float*)d_in[4];
    const float* bstd  = (const float*)d_in[5];
    const float* Wdts  = (const float*)d_in[6];
    const float* bdts  = (const float*)d_in[7];
    const float* Wlin  = (const float*)d_in[8];
    const float* blin  = (const float*)d_in[9];
    const float* alpha = (const float*)d_in[10];

    int N = in_sizes[0] / D;   // 50000
    int E = in_sizes[1] / 2;   // 800000

    char* p = (char*)d_ws;
    auto alloc = [&](size_t bytes) {
        char* q = p;
        p += (bytes + 255) & ~(size_t)255;
        return q;
    };
    // cnt/cur kept contiguous -> single memset
    int* cnt_in  = (int*)alloc((size_t)N * 4);
    int* cnt_out = (int*)alloc((size_t)N * 4);
    int* cur_in  = (int*)alloc((size_t)N * 4);
    int* cur_out = (int*)alloc((size_t)N * 4);
    char* zero_end = p;
    int* row_in  = (int*)alloc((size_t)(N + 1) * 4);
    int* row_out = (int*)alloc((size_t)(N + 1) * 4);
    int* col_in  = (int*)alloc((size_t)E * 4);
    int* col_out = (int*)alloc((size_t)E * 4);
    short* xb    = (short*)alloc((size_t)N * D * 2);
    short* hb    = (short*)alloc((size_t)N * D * 2);
    short* wt    = (short*)alloc((size_t)9 * D * D * 2);
    short* wlt   = (short*)alloc((size_t)D * OUTD * 2);
    float* bcombp = (float*)alloc((size_t)LAYERS * D * 4);
    short* t1b   = (short*)alloc((size_t)N * D * 2);
    uint32* t2q  = (uint32*)alloc((size_t)N * 32 * 4);   // fp8, 128 B/row
    uint32* t3q  = (uint32*)alloc((size_t)N * 32 * 4);
    short* jkb   = (short*)alloc((size_t)N * D * 2);

    const int* srcp = ei;
    const int* dstp = ei + E;

    hipMemsetAsync(cnt_in, 0, (size_t)(zero_end - (char*)cnt_in), stream);

    prep<<<CNT_BLOCKS + CVX_BLOCKS + 11, 256, 0, stream>>>(
        srcp, dstp, E, N, cnt_in, cnt_out, x, xb,
        Wself, Wstd, Wdts, Wlin, bself, bstd, bdts, alpha, wt, wlt, bcombp);
    scan2<<<2, 1024, 0, stream>>>(cnt_in, row_in, cnt_out, row_out, N);

    int gm = ceil_div(N, 128);
    fill_gemm0<<<FILL_BLOCKS + 3 * gm, 256, 0, stream>>>(
        srcp, dstp, E, N, row_in, row_out, cur_in, cur_out, col_in, col_out,
        xb, wt, t1b, t2q, t3q);

    for (int l = 0; l < LAYERS; l++) {
        agg_epilogue<<<ceil_div(N, 4), 256, 0, stream>>>(
            t1b, t2q, t3q, bcombp + (size_t)l * D,
            row_in, col_in, row_out, col_out, alpha,
            (l == LAYERS - 1) ? nullptr : hb, jkb, (l == 0) ? 1 : 0, N);
        if (l < LAYERS - 1)
            gemm3_k<<<dim3(gm, 1, 3), 256, 0, stream>>>(hb, N, wt + (size_t)(l + 1) * 3 * D * D,
                                                        t1b, t2q, t3q);
    }
    gemm_out_mfma<<<gm, 256, 0, stream>>>(jkb, N, wlt, blin, (float*)d_out);
}

// Round 8
// 459.206 us; speedup vs baseline: 1.1459x; 1.1127x over previous
//
#include <hip/hip_runtime.h>

#define D 128
#define OUTD 64
#define LAYERS 3
#define MAXBK 512   // max buckets (node>>7); N=50000 -> 391

typedef __attribute__((ext_vector_type(8))) short short8;
typedef __attribute__((ext_vector_type(4))) float float4v;
typedef __attribute__((ext_vector_type(2))) float floatx2;
typedef unsigned int uint32;

static inline int ceil_div(int a, int b) { return (a + b - 1) / b; }

__device__ __forceinline__ unsigned short f2bf(float f) {
    unsigned int u = __float_as_uint(f);
    unsigned int r = u + 0x7FFFu + ((u >> 16) & 1u);
    return (unsigned short)(r >> 16);
}

// feature permutation: storage element position of logical feature f.
__device__ __forceinline__ int fperm(int f) { return (f & 15) * 8 + (f >> 4); }

// ---------------- prep: per-node count + bucket hist + all converts ----------------

#define CNT_BLOCKS 1280   // 8 node-range groups x 160 blocks
#define BH_BLOCKS  64     // bucket-histogram blocks (edge-range partitioned)
#define CVX_BLOCKS 1044

__global__ __launch_bounds__(256)
void prep(const int* __restrict__ src, const int* __restrict__ dst, int E, int N, int NBK,
          int* cnt_in, int* cnt_out, int* bc_in, int* bc_out,
          const float* __restrict__ x, short* __restrict__ xb,
          const float* __restrict__ Wself, const float* __restrict__ Wstd,
          const float* __restrict__ Wdts, const float* __restrict__ Wlin,
          const float* __restrict__ bself, const float* __restrict__ bstd,
          const float* __restrict__ bdts, const float* __restrict__ alpha_p,
          short* __restrict__ wt, short* __restrict__ wlt, float* __restrict__ bcombp) {
    __shared__ int bh[2 * MAXBK];
    int b = blockIdx.x;
    if (b < CNT_BLOCKS) {
        // node-partitioned per-node degree count (XCD-local atomics)
        int xcd = b & 7, chunk = b >> 3;
        int lo = (int)((long long)xcd * N / 8);
        int hi = (int)((long long)(xcd + 1) * N / 8);
        int stride = (CNT_BLOCKS >> 3) * 256;
        for (int e = chunk * 256 + threadIdx.x; e < E; e += stride) {
            int s = src[e], d = dst[e];
            if (d >= lo && d < hi) atomicAdd(&cnt_in[d], 1);
            if (s >= lo && s < hi) atomicAdd(&cnt_out[s], 1);
        }
    } else if (b < CNT_BLOCKS + BH_BLOCKS) {
        // per-bucket edge histograms (LDS staged, one global merge)
        int hb = b - CNT_BLOCKS;
        for (int i = threadIdx.x; i < 2 * MAXBK; i += 256) bh[i] = 0;
        __syncthreads();
        int per = (E + BH_BLOCKS - 1) / BH_BLOCKS;
        int lo = hb * per, hi = min(E, lo + per);
        for (int e = lo + threadIdx.x; e < hi; e += 256) {
            int s = src[e], d = dst[e];
            atomicAdd(&bh[d >> 7], 1);
            atomicAdd(&bh[MAXBK + (s >> 7)], 1);
        }
        __syncthreads();
        for (int i = threadIdx.x; i < NBK; i += 256) {
            if (bh[i]) atomicAdd(&bc_in[i], bh[i]);
            if (bh[MAXBK + i]) atomicAdd(&bc_out[i], bh[MAXBK + i]);
        }
    } else if (b < CNT_BLOCKS + BH_BLOCKS + CVX_BLOCKS) {
        int total = N * 16;
        for (int i = (b - CNT_BLOCKS - BH_BLOCKS) * 256 + threadIdx.x; i < total; i += CVX_BLOCKS * 256) {
            int n = i >> 4, q = i & 15;
            const float* xr = x + (size_t)n * D + q;
            short8 s;
            #pragma unroll
            for (int fh = 0; fh < 8; fh++) s[fh] = (short)f2bf(xr[fh * 16]);
            *(short8*)(xb + (size_t)n * D + q * 8) = s;
        }
    } else {
        int cb = b - CNT_BLOCKS - BH_BLOCKS - CVX_BLOCKS;   // 0..10
        if (cb < 9) {
            int l = cb / 3, m = cb % 3;
            const float* W = (m == 0 ? Wself : (m == 1 ? Wstd : Wdts)) + (size_t)l * D * D;
            short* o = wt + (size_t)cb * D * D;
            for (int idx = threadIdx.x; idx < D * D; idx += 256) {
                int k = idx >> 7, n = idx & 127;
                o[n * D + fperm(k)] = (short)f2bf(W[idx]);
            }
        } else if (cb == 9) {
            for (int idx = threadIdx.x; idx < D * OUTD; idx += 256) {
                int k = idx >> 6, n = idx & 63;
                wlt[n * D + fperm(k)] = (short)f2bf(Wlin[idx]);
            }
        } else {
            float a = alpha_p[0];
            for (int i = threadIdx.x; i < LAYERS * D; i += 256) {
                int l = i >> 7, j = i & 127;
                bcombp[l * D + fperm(j)] = bself[i] + (1.0f - a) * bstd[i] + a * bdts[i];
            }
        }
    }
}

// ---------------- scans: blocks 0/1 per-node, blocks 2/3 per-bucket (dual write) ----------------

__global__ __launch_bounds__(1024)
void scan4(const int* __restrict__ cnt_in, int* __restrict__ row_in,
           const int* __restrict__ cnt_out, int* __restrict__ row_out, int N,
           const int* __restrict__ bc_in, int* __restrict__ off_in, int* __restrict__ bcur_in,
           const int* __restrict__ bc_out, int* __restrict__ off_out, int* __restrict__ bcur_out,
           int NBK) {
    const int* cnt; int* row; int* cur = nullptr; int n;
    if (blockIdx.x == 0)      { cnt = cnt_in;  row = row_in;  n = N; }
    else if (blockIdx.x == 1) { cnt = cnt_out; row = row_out; n = N; }
    else if (blockIdx.x == 2) { cnt = bc_in;   row = off_in;  cur = bcur_in;  n = NBK; }
    else                      { cnt = bc_out;  row = off_out; cur = bcur_out; n = NBK; }
    __shared__ int wsum[16];
    __shared__ int chunk_total;
    int lane = threadIdx.x & 63;
    int w = threadIdx.x >> 6;
    int carry = 0;
    int v_next = (threadIdx.x < n) ? cnt[threadIdx.x] : 0;
    for (int base = 0; base < n; base += 1024) {
        int i = base + threadIdx.x;
        int v = v_next;
        int inext = i + 1024;
        v_next = (inext < n) ? cnt[inext] : 0;
        int x = v;
        #pragma unroll
        for (int off = 1; off < 64; off <<= 1) {
            int y = __shfl_up(x, off, 64);
            if (lane >= off) x += y;
        }
        if (lane == 63) wsum[w] = x;
        __syncthreads();
        if (w == 0 && lane < 16) {
            int s = wsum[lane];
            #pragma unroll
            for (int off = 1; off < 16; off <<= 1) {
                int y = __shfl_up(s, off, 16);
                if (lane >= off) s += y;
            }
            wsum[lane] = s;
            if (lane == 15) chunk_total = s;
        }
        __syncthreads();
        int wpre = (w == 0) ? 0 : wsum[w - 1];
        if (i < n) {
            int val = carry + wpre + (x - v);
            row[i] = val;
            if (cur) cur[i] = val;
        }
        carry += chunk_total;
        __syncthreads();
    }
    if (threadIdx.x == 0) row[n] = carry;
}

// ---------------- slim GEMM body: A direct from global, B staged in caller's LDS ----------------

__device__ __forceinline__ void gemm3_body(int mtile, int z, const short* __restrict__ Abf,
                                           int M, const short* __restrict__ wt3,
                                           short* __restrict__ t1b,
                                           uint32* __restrict__ t2q, uint32* __restrict__ t3q,
                                           short* Bs) {   // Bs: 128*136 shorts
    int tid = threadIdx.x;
    int m0 = mtile * 128;
    const short* Bt = wt3 + (size_t)z * D * D;

    #pragma unroll
    for (int i = 0; i < 8; i++) {
        int v = tid + i * 256;
        int row = v >> 4, c8 = v & 15;
        *(short8*)&Bs[row * 136 + c8 * 8] = *(const short8*)(Bt + (size_t)row * D + c8 * 8);
    }
    __syncthreads();

    int wave = tid >> 6, lane = tid & 63;
    int quad = lane >> 4, r16 = lane & 15;
    int mrow = wave * 32;
    int gr0 = m0 + mrow + r16;
    int gr1 = gr0 + 16;

    float4v acc[2][8];
    #pragma unroll
    for (int a = 0; a < 2; a++)
        #pragma unroll
        for (int b = 0; b < 8; b++)
            acc[a][b] = (float4v){0.f, 0.f, 0.f, 0.f};

    #pragma unroll
    for (int kc = 0; kc < 4; kc++) {
        short8 a0 = {0, 0, 0, 0, 0, 0, 0, 0};
        short8 a1 = {0, 0, 0, 0, 0, 0, 0, 0};
        if (gr0 < M) a0 = *(const short8*)(Abf + (size_t)gr0 * D + kc * 32 + quad * 8);
        if (gr1 < M) a1 = *(const short8*)(Abf + (size_t)gr1 * D + kc * 32 + quad * 8);
        #pragma unroll
        for (int nt = 0; nt < 8; nt++) {
            short8 b = *(const short8*)&Bs[(nt * 16 + r16) * 136 + kc * 32 + quad * 8];
            acc[0][nt] = __builtin_amdgcn_mfma_f32_16x16x32_bf16(a0, b, acc[0][nt], 0, 0, 0);
            acc[1][nt] = __builtin_amdgcn_mfma_f32_16x16x32_bf16(a1, b, acc[1][nt], 0, 0, 0);
        }
    }

    #pragma unroll
    for (int rt = 0; rt < 2; rt++)
        #pragma unroll
        for (int reg = 0; reg < 4; reg++) {
            int row = m0 + mrow + rt * 16 + quad * 4 + reg;
            if (row >= M) continue;
            if (z == 0) {
                short8 s8;
                #pragma unroll
                for (int nt = 0; nt < 8; nt++) s8[nt] = (short)f2bf(acc[rt][nt][reg]);
                *(short8*)(t1b + (size_t)row * D + r16 * 8) = s8;
            } else {
                uint32 u0 = __builtin_amdgcn_cvt_pk_fp8_f32(acc[rt][0][reg], acc[rt][1][reg], 0, false);
                u0 = __builtin_amdgcn_cvt_pk_fp8_f32(acc[rt][2][reg], acc[rt][3][reg], u0, true);
                uint32 u1 = __builtin_amdgcn_cvt_pk_fp8_f32(acc[rt][4][reg], acc[rt][5][reg], 0, false);
                u1 = __builtin_amdgcn_cvt_pk_fp8_f32(acc[rt][6][reg], acc[rt][7][reg], u1, true);
                uint32* dq = ((z == 1) ? t2q : t3q) + (size_t)row * 32 + r16 * 2;
                *(uint2*)dq = make_uint2(u0, u1);
            }
        }
}

// ---------------- build: binned edge append (dense stores) + fused layer-0 GEMM ----------------
// Append blocks: two-pass over their edge range. LDS hist -> one global atomic
// reserve per (block,bucket) -> LDS-cursor append of packed 4B records
// (neighbor<<7 | node&127). Each block's per-bucket range (~64B) is written
// densely in time -> full write combining. Requires N < 2^25.

#define AP_BLOCKS 128

__global__ __launch_bounds__(256)
void build_gemm0(const int* __restrict__ src, const int* __restrict__ dst, int E, int N,
                 int NBK, int* bcur_in, int* bcur_out,
                 uint32* __restrict__ ebuf_in, uint32* __restrict__ ebuf_out,
                 const short* __restrict__ xb, const short* __restrict__ wt,
                 short* __restrict__ t1b, uint32* __restrict__ t2q, uint32* __restrict__ t3q) {
    __shared__ __align__(16) short smem[128 * 136];
    int b = blockIdx.x;
    if (b < AP_BLOCKS) {
        int* h_in = (int*)smem;          // MAXBK
        int* h_out = h_in + MAXBK;       // MAXBK
        for (int i = threadIdx.x; i < 2 * MAXBK; i += 256) h_in[i] = 0;
        __syncthreads();
        int per = (E + AP_BLOCKS - 1) / AP_BLOCKS;
        int lo = b * per, hi = min(E, lo + per);
        for (int e = lo + threadIdx.x; e < hi; e += 256) {
            int s = src[e], d = dst[e];
            atomicAdd(&h_in[d >> 7], 1);
            atomicAdd(&h_out[s >> 7], 1);
        }
        __syncthreads();
        for (int i = threadIdx.x; i < NBK; i += 256) {
            int c = h_in[i];
            h_in[i] = c ? atomicAdd(&bcur_in[i], c) : 0;
            int c2 = h_out[i];
            h_out[i] = c2 ? atomicAdd(&bcur_out[i], c2) : 0;
        }
        __syncthreads();
        for (int e = lo + threadIdx.x; e < hi; e += 256) {
            int s = src[e], d = dst[e];
            int p = atomicAdd(&h_in[d >> 7], 1);
            ebuf_in[p] = ((uint32)s << 7) | (uint32)(d & 127);
            int q = atomicAdd(&h_out[s >> 7], 1);
            ebuf_out[q] = ((uint32)d << 7) | (uint32)(s & 127);
        }
    } else {
        int g = b - AP_BLOCKS;
        gemm3_body(g / 3, g % 3, xb, N, wt, t1b, t2q, t3q, smem);
    }
}

// ---------------- bucket_fill: per-bucket CSR col fill (dense 8KB store window) ----------------

__global__ __launch_bounds__(256)
void bucket_fill(const uint32* __restrict__ ebuf_in, const int* __restrict__ off_in,
                 const int* __restrict__ row_in, int* __restrict__ col_in,
                 const uint32* __restrict__ ebuf_out, const int* __restrict__ off_out,
                 const int* __restrict__ row_out, int* __restrict__ col_out,
                 int N, int NBK) {
    __shared__ int lcur[128];
    int b = blockIdx.x;
    const uint32* ebuf; const int* off; const int* row; int* col; int k;
    if (b < NBK) { ebuf = ebuf_in;  off = off_in;  row = row_in;  col = col_in;  k = b; }
    else         { ebuf = ebuf_out; off = off_out; row = row_out; col = col_out; k = b - NBK; }
    int nb = k << 7;
    if (threadIdx.x < 128) {
        int node = nb + threadIdx.x;
        lcur[threadIdx.x] = (node < N) ? row[node] : 0;
    }
    __syncthreads();
    int lo = off[k], hi = off[k + 1];
    for (int r = lo + threadIdx.x; r < hi; r += 256) {
        uint32 rec = ebuf[r];
        int slot = atomicAdd(&lcur[rec & 127], 1);
        col[slot] = (int)(rec >> 7);
    }
}

__global__ __launch_bounds__(256)
void gemm3_k(const short* __restrict__ hin, int M, const short* __restrict__ wt3,
             short* __restrict__ t1b, uint32* __restrict__ t2q, uint32* __restrict__ t3q) {
    __shared__ __align__(16) short smem[128 * 136];
    gemm3_body(blockIdx.x, blockIdx.z, hin, M, wt3, t1b, t2q, t3q, smem);
}

// ---------------- Final GEMM (MFMA, slim) ----------------

__global__ __launch_bounds__(256)
void gemm_out_mfma(const short* __restrict__ jkb, int M, const short* __restrict__ wlt,
                   const float* __restrict__ blin, float* __restrict__ Cout) {
    __shared__ __align__(16) short Bs[64][136];
    int tid = threadIdx.x;
    int m0 = blockIdx.x * 128;

    #pragma unroll
    for (int i = 0; i < 4; i++) {
        int v = tid + i * 256;
        int row = v >> 4, c8 = v & 15;
        *(short8*)&Bs[row][c8 * 8] = *(const short8*)(wlt + (size_t)row * D + c8 * 8);
    }
    __syncthreads();

    int wave = tid >> 6, lane = tid & 63;
    int quad = lane >> 4, r16 = lane & 15;
    int mrow = wave * 32;
    int gr0 = m0 + mrow + r16;
    int gr1 = gr0 + 16;

    float4v acc[2][4];
    #pragma unroll
    for (int a = 0; a < 2; a++)
        #pragma unroll
        for (int b = 0; b < 4; b++)
            acc[a][b] = (float4v){0.f, 0.f, 0.f, 0.f};

    #pragma unroll
    for (int kc = 0; kc < 4; kc++) {
        short8 a0 = {0, 0, 0, 0, 0, 0, 0, 0};
        short8 a1 = {0, 0, 0, 0, 0, 0, 0, 0};
        if (gr0 < M) a0 = *(const short8*)(jkb + (size_t)gr0 * D + kc * 32 + quad * 8);
        if (gr1 < M) a1 = *(const short8*)(jkb + (size_t)gr1 * D + kc * 32 + quad * 8);
        #pragma unroll
        for (int nt = 0; nt < 4; nt++) {
            short8 b = *(const short8*)&Bs[nt * 16 + r16][kc * 32 + quad * 8];
            acc[0][nt] = __builtin_amdgcn_mfma_f32_16x16x32_bf16(a0, b, acc[0][nt], 0, 0, 0);
            acc[1][nt] = __builtin_amdgcn_mfma_f32_16x16x32_bf16(a1, b, acc[1][nt], 0, 0, 0);
        }
    }

    #pragma unroll
    for (int rt = 0; rt < 2; rt++)
        #pragma unroll
        for (int nt = 0; nt < 4; nt++)
            #pragma unroll
            for (int reg = 0; reg < 4; reg++) {
                int row = m0 + mrow + rt * 16 + quad * 4 + reg;
                int col = nt * 16 + r16;
                if (row < M) Cout[(size_t)row * OUTD + col] = acc[rt][nt][reg] + blin[col];
            }
}

// ---------------- Fused aggregation: fp8 gathers, 2 rows/load, dual-stream ----------------

__global__ __launch_bounds__(256)
void agg_epilogue(const short* __restrict__ t1b,
                  const uint32* __restrict__ t2q, const uint32* __restrict__ t3q,
                  const float* __restrict__ bcombp,
                  const int* __restrict__ row_in, const int* __restrict__ col_in,
                  const int* __restrict__ row_out, const int* __restrict__ col_out,
                  const float* __restrict__ alpha_p,
                  short* __restrict__ h_out, short* __restrict__ jkb,
                  int first, int N) {
    int wv = threadIdx.x >> 6;
    int lane = threadIdx.x & 63;
    int n = blockIdx.x * 4 + wv;
    if (n >= N) return;
    float a = alpha_p[0];
    int s_in = row_in[n], e_in = row_in[n + 1];
    int s_out = row_out[n], e_out = row_out[n + 1];
    int din = e_in - s_in, dout = e_out - s_out;
    bool lower = lane < 32;
    uint32 off32 = lane & 31;

    floatx2 ai0 = {0.f, 0.f}, ai1 = {0.f, 0.f};
    floatx2 ao0 = {0.f, 0.f}, ao1 = {0.f, 0.f};

    int pin = s_in, pout = s_out;
    while (pin < e_in || pout < e_out) {
        int m_in = e_in - pin;   if (m_in > 64) m_in = 64;   if (m_in < 0) m_in = 0;
        int m_out = e_out - pout; if (m_out > 64) m_out = 64; if (m_out < 0) m_out = 0;
        int idxi = (lane < m_in) ? col_in[pin + lane] : 0;
        int idxo = (lane < m_out) ? col_out[pout + lane] : 0;
        int fi = m_in & ~15, fo = m_out & ~15;
        int ji = 0, jo = 0;
        while (ji < fi || jo < fo) {
            uint32 wi[8], wo[8];
            bool di = ji < fi, dw = jo < fo;
            if (di) {
                #pragma unroll
                for (int t = 0; t < 8; t++) {
                    int u0 = __builtin_amdgcn_readlane(idxi, ji + 2 * t);
                    int u1 = __builtin_amdgcn_readlane(idxi, ji + 2 * t + 1);
                    int us = lower ? u0 : u1;
                    wi[t] = t2q[(size_t)us * 32 + off32];
                }
            }
            if (dw) {
                #pragma unroll
                for (int t = 0; t < 8; t++) {
                    int u0 = __builtin_amdgcn_readlane(idxo, jo + 2 * t);
                    int u1 = __builtin_amdgcn_readlane(idxo, jo + 2 * t + 1);
                    int us = lower ? u0 : u1;
                    wo[t] = t3q[(size_t)us * 32 + off32];
                }
            }
            if (di) {
                #pragma unroll
                for (int t = 0; t < 8; t++) {
                    ai0 += __builtin_amdgcn_cvt_pk_f32_fp8(wi[t], false);
                    ai1 += __builtin_amdgcn_cvt_pk_f32_fp8(wi[t], true);
                }
                ji += 16;
            }
            if (dw) {
                #pragma unroll
                for (int t = 0; t < 8; t++) {
                    ao0 += __builtin_amdgcn_cvt_pk_f32_fp8(wo[t], false);
                    ao1 += __builtin_amdgcn_cvt_pk_f32_fp8(wo[t], true);
                }
                jo += 16;
            }
        }
        int ri = m_in - fi, ro = m_out - fo;   // 0..15
        if (ri | ro) {
            uint32 wi[8], wo[8];
            #pragma unroll
            for (int t = 0; t < 8; t++) { wi[t] = 0u; wo[t] = 0u; }
            #pragma unroll
            for (int t = 0; t < 8; t++) {
                if (2 * t < ri) {
                    int j0 = fi + 2 * t;
                    int j1 = (2 * t + 1 < ri) ? j0 + 1 : j0;
                    int u0 = __builtin_amdgcn_readlane(idxi, j0);
                    int u1 = __builtin_amdgcn_readlane(idxi, j1);
                    int us = lower ? u0 : u1;
                    uint32 v = t2q[(size_t)us * 32 + off32];
                    if (2 * t + 1 >= ri) v = lower ? v : 0u;
                    wi[t] = v;
                }
            }
            #pragma unroll
            for (int t = 0; t < 8; t++) {
                if (2 * t < ro) {
                    int j0 = fo + 2 * t;
                    int j1 = (2 * t + 1 < ro) ? j0 + 1 : j0;
                    int u0 = __builtin_amdgcn_readlane(idxo, j0);
                    int u1 = __builtin_amdgcn_readlane(idxo, j1);
                    int us = lower ? u0 : u1;
                    uint32 v = t3q[(size_t)us * 32 + off32];
                    if (2 * t + 1 >= ro) v = lower ? v : 0u;
                    wo[t] = v;
                }
            }
            #pragma unroll
            for (int t = 0; t < 8; t++) {
                ai0 += __builtin_amdgcn_cvt_pk_f32_fp8(wi[t], false);
                ai1 += __builtin_amdgcn_cvt_pk_f32_fp8(wi[t], true);
                ao0 += __builtin_amdgcn_cvt_pk_f32_fp8(wo[t], false);
                ao1 += __builtin_amdgcn_cvt_pk_f32_fp8(wo[t], true);
            }
        }
        pin += m_in; pout += m_out;
    }

    ai0.x += __shfl_xor(ai0.x, 32, 64); ai0.y += __shfl_xor(ai0.y, 32, 64);
    ai1.x += __shfl_xor(ai1.x, 32, 64); ai1.y += __shfl_xor(ai1.y, 32, 64);
    ao0.x += __shfl_xor(ao0.x, 32, 64); ao0.y += __shfl_xor(ao0.y, 32, 64);
    ao1.x += __shfl_xor(ao1.x, 32, 64); ao1.y += __shfl_xor(ao1.y, 32, 64);

    if (lower) {
        float win = (1.0f - a) / (float)max(din, 1);
        float wout = a / (float)max(dout, 1);
        int L = lane;   // 0..31 -> permuted elements 4L..4L+3
        uint2 tv = *(const uint2*)(t1b + (size_t)n * D + 4 * L);
        float4 bc = *(const float4*)(bcombp + 4 * L);
        float t0 = __uint_as_float(tv.x << 16);
        float t1 = __uint_as_float(tv.x & 0xFFFF0000u);
        float t2 = __uint_as_float(tv.y << 16);
        float t3 = __uint_as_float(tv.y & 0xFFFF0000u);
        float h0 = fmaxf(t0 + bc.x + win * ai0.x + wout * ao0.x, 0.f);
        float h1 = fmaxf(t1 + bc.y + win * ai0.y + wout * ao0.y, 0.f);
        float h2 = fmaxf(t2 + bc.z + win * ai1.x + wout * ao1.x, 0.f);
        float h3 = fmaxf(t3 + bc.w + win * ai1.y + wout * ao1.y, 0.f);
        uint32 p0 = (uint32)f2bf(h0) | ((uint32)f2bf(h1) << 16);
        uint32 p1 = (uint32)f2bf(h2) | ((uint32)f2bf(h3) << 16);
        if (h_out) *(uint2*)(h_out + (size_t)n * D + 4 * L) = make_uint2(p0, p1);
        uint2* jp = (uint2*)(jkb + (size_t)n * D + 4 * L);
        if (first) {
            *jp = make_uint2(p0, p1);
        } else {
            uint2 old = *jp;
            uint32 q0 = max(old.x & 0xFFFFu, p0 & 0xFFFFu) | max(old.x & 0xFFFF0000u, p0 & 0xFFFF0000u);
            uint32 q1 = max(old.y & 0xFFFFu, p1 & 0xFFFFu) | max(old.y & 0xFFFF0000u, p1 & 0xFFFF0000u);
            *jp = make_uint2(q0, q1);
        }
    }
}

// ---------------- launch ----------------

extern "C" void kernel_launch(void* const* d_in, const int* in_sizes, int n_in,
                              void* d_out, int out_size, void* d_ws, size_t ws_size,
                              hipStream_t stream) {
    const float* x     = (const float*)d_in[0];
    const int*   ei    = (const int*)d_in[1];
    const float* Wself = (const float*)d_in[2];
    const float* bself = (const float*)d_in[3];
    const float* Wstd  = (const float*)d_in[4];
    const float* bstd  = (const float*)d_in[5];
    const float* Wdts  = (const float*)d_in[6];
    const float* bdts  = (const float*)d_in[7];
    const float* Wlin  = (const float*)d_in[8];
    const float* blin  = (const float*)d_in[9];
    const float* alpha = (const float*)d_in[10];

    int N = in_sizes[0] / D;   // 50000
    int E = in_sizes[1] / 2;   // 800000
    int NBK = ceil_div(N, 128);

    char* p = (char*)d_ws;
    auto alloc = [&](size_t bytes) {
        char* q = p;
        p += (bytes + 255) & ~(size_t)255;
        return q;
    };
    // zero-init region: per-node counts + bucket counts (single memset)
    int* cnt_in  = (int*)alloc((size_t)N * 4);
    int* cnt_out = (int*)alloc((size_t)N * 4);
    int* bc_in   = (int*)alloc((size_t)MAXBK * 4);
    int* bc_out  = (int*)alloc((size_t)MAXBK * 4);
    char* zero_end = p;
    int* row_in   = (int*)alloc((size_t)(N + 1) * 4);
    int* row_out  = (int*)alloc((size_t)(N + 1) * 4);
    int* off_in   = (int*)alloc((size_t)(MAXBK + 1) * 4);
    int* off_out  = (int*)alloc((size_t)(MAXBK + 1) * 4);
    int* bcur_in  = (int*)alloc((size_t)(MAXBK + 1) * 4);
    int* bcur_out = (int*)alloc((size_t)(MAXBK + 1) * 4);
    uint32* ebuf_in  = (uint32*)alloc((size_t)E * 4);
    uint32* ebuf_out = (uint32*)alloc((size_t)E * 4);
    int* col_in  = (int*)alloc((size_t)E * 4);
    int* col_out = (int*)alloc((size_t)E * 4);
    short* xb    = (short*)alloc((size_t)N * D * 2);
    short* hb    = (short*)alloc((size_t)N * D * 2);
    short* wt    = (short*)alloc((size_t)9 * D * D * 2);
    short* wlt   = (short*)alloc((size_t)D * OUTD * 2);
    float* bcombp = (float*)alloc((size_t)LAYERS * D * 4);
    short* t1b   = (short*)alloc((size_t)N * D * 2);
    uint32* t2q  = (uint32*)alloc((size_t)N * 32 * 4);   // fp8, 128 B/row
    uint32* t3q  = (uint32*)alloc((size_t)N * 32 * 4);
    short* jkb   = (short*)alloc((size_t)N * D * 2);

    const int* srcp = ei;
    const int* dstp = ei + E;

    hipMemsetAsync(cnt_in, 0, (size_t)(zero_end - (char*)cnt_in), stream);

    prep<<<CNT_BLOCKS + BH_BLOCKS + CVX_BLOCKS + 11, 256, 0, stream>>>(
        srcp, dstp, E, N, NBK, cnt_in, cnt_out, bc_in, bc_out, x, xb,
        Wself, Wstd, Wdts, Wlin, bself, bstd, bdts, alpha, wt, wlt, bcombp);
    scan4<<<4, 1024, 0, stream>>>(cnt_in, row_in, cnt_out, row_out, N,
                                  bc_in, off_in, bcur_in, bc_out, off_out, bcur_out, NBK);

    int gm = ceil_div(N, 128);
    build_gemm0<<<AP_BLOCKS + 3 * gm, 256, 0, stream>>>(
        srcp, dstp, E, N, NBK, bcur_in, bcur_out, ebuf_in, ebuf_out,
        xb, wt, t1b, t2q, t3q);
    bucket_fill<<<2 * NBK, 256, 0, stream>>>(ebuf_in, off_in, row_in, col_in,
                                             ebuf_out, off_out, row_out, col_out, N, NBK);

    for (int l = 0; l < LAYERS; l++) {
        agg_epilogue<<<ceil_div(N, 4), 256, 0, stream>>>(
            t1b, t2q, t3q, bcombp + (size_t)l * D,
            row_in, col_in, row_out, col_out, alpha,
            (l == LAYERS - 1) ? nullptr : hb, jkb, (l == 0) ? 1 : 0, N);
        if (l < LAYERS - 1)
            gemm3_k<<<dim3(gm, 1, 3), 256, 0, stream>>>(hb, N, wt + (size_t)(l + 1) * 3 * D * D,
                                                        t1b, t2q, t3q);
    }
    gemm_out_mfma<<<gm, 256, 0, stream>>>(jkb, N, wlt, blin, (float*)d_out);
}

// Round 9
// 365.765 us; speedup vs baseline: 1.4386x; 1.2555x over previous
//
#include <hip/hip_runtime.h>

#define D 128
#define OUTD 64
#define LAYERS 3
#define MAXBK 512   // max buckets (node>>7); N=50000 -> 391

typedef __attribute__((ext_vector_type(8))) short short8;
typedef __attribute__((ext_vector_type(4))) float float4v;
typedef __attribute__((ext_vector_type(2))) float floatx2;
typedef unsigned int uint32;

static inline int ceil_div(int a, int b) { return (a + b - 1) / b; }

__device__ __forceinline__ unsigned short f2bf(float f) {
    unsigned int u = __float_as_uint(f);
    unsigned int r = u + 0x7FFFu + ((u >> 16) & 1u);
    return (unsigned short)(r >> 16);
}

// feature permutation: storage element position of logical feature f.
__device__ __forceinline__ int fperm(int f) { return (f & 15) * 8 + (f >> 4); }

// ---------------- prep: bucket hist + all converts (NO per-node counting) ----------------

#define BH_BLOCKS  64     // bucket-histogram blocks (edge-range partitioned)
#define CVX_BLOCKS 1044

__global__ __launch_bounds__(256)
void prep(const int* __restrict__ src, const int* __restrict__ dst, int E, int N, int NBK,
          int* bc_in, int* bc_out,
          const float* __restrict__ x, short* __restrict__ xb,
          const float* __restrict__ Wself, const float* __restrict__ Wstd,
          const float* __restrict__ Wdts, const float* __restrict__ Wlin,
          const float* __restrict__ bself, const float* __restrict__ bstd,
          const float* __restrict__ bdts, const float* __restrict__ alpha_p,
          short* __restrict__ wt, short* __restrict__ wlt, float* __restrict__ bcombp) {
    __shared__ int bh[2 * MAXBK];
    int b = blockIdx.x;
    if (b < BH_BLOCKS) {
        // per-bucket edge histograms (LDS staged, one global merge)
        for (int i = threadIdx.x; i < 2 * MAXBK; i += 256) bh[i] = 0;
        __syncthreads();
        int per = (E + BH_BLOCKS - 1) / BH_BLOCKS;
        int lo = b * per, hi = min(E, lo + per);
        for (int e = lo + threadIdx.x; e < hi; e += 256) {
            int s = src[e], d = dst[e];
            atomicAdd(&bh[d >> 7], 1);
            atomicAdd(&bh[MAXBK + (s >> 7)], 1);
        }
        __syncthreads();
        for (int i = threadIdx.x; i < NBK; i += 256) {
            if (bh[i]) atomicAdd(&bc_in[i], bh[i]);
            if (bh[MAXBK + i]) atomicAdd(&bc_out[i], bh[MAXBK + i]);
        }
    } else if (b < BH_BLOCKS + CVX_BLOCKS) {
        int total = N * 16;
        for (int i = (b - BH_BLOCKS) * 256 + threadIdx.x; i < total; i += CVX_BLOCKS * 256) {
            int n = i >> 4, q = i & 15;
            const float* xr = x + (size_t)n * D + q;
            short8 s;
            #pragma unroll
            for (int fh = 0; fh < 8; fh++) s[fh] = (short)f2bf(xr[fh * 16]);
            *(short8*)(xb + (size_t)n * D + q * 8) = s;
        }
    } else {
        int cb = b - BH_BLOCKS - CVX_BLOCKS;   // 0..10
        if (cb < 9) {
            int l = cb / 3, m = cb % 3;
            const float* W = (m == 0 ? Wself : (m == 1 ? Wstd : Wdts)) + (size_t)l * D * D;
            short* o = wt + (size_t)cb * D * D;
            for (int idx = threadIdx.x; idx < D * D; idx += 256) {
                int k = idx >> 7, n = idx & 127;
                o[n * D + fperm(k)] = (short)f2bf(W[idx]);
            }
        } else if (cb == 9) {
            for (int idx = threadIdx.x; idx < D * OUTD; idx += 256) {
                int k = idx >> 6, n = idx & 63;
                wlt[n * D + fperm(k)] = (short)f2bf(Wlin[idx]);
            }
        } else {
            float a = alpha_p[0];
            for (int i = threadIdx.x; i < LAYERS * D; i += 256) {
                int l = i >> 7, j = i & 127;
                bcombp[l * D + fperm(j)] = bself[i] + (1.0f - a) * bstd[i] + a * bdts[i];
            }
        }
    }
}

// ---------------- bucket-offset scans (391 elements each; writes off + bcur) ----------------

__global__ __launch_bounds__(1024)
void scan2(const int* __restrict__ bc_in, int* __restrict__ off_in, int* __restrict__ bcur_in,
           const int* __restrict__ bc_out, int* __restrict__ off_out, int* __restrict__ bcur_out,
           int n) {
    const int* cnt = blockIdx.x ? bc_out : bc_in;
    int* row = blockIdx.x ? off_out : off_in;
    int* cur = blockIdx.x ? bcur_out : bcur_in;
    __shared__ int wsum[16];
    __shared__ int chunk_total;
    int lane = threadIdx.x & 63;
    int w = threadIdx.x >> 6;
    int carry = 0;
    int v_next = (threadIdx.x < n) ? cnt[threadIdx.x] : 0;
    for (int base = 0; base < n; base += 1024) {
        int i = base + threadIdx.x;
        int v = v_next;
        int inext = i + 1024;
        v_next = (inext < n) ? cnt[inext] : 0;
        int x = v;
        #pragma unroll
        for (int off = 1; off < 64; off <<= 1) {
            int y = __shfl_up(x, off, 64);
            if (lane >= off) x += y;
        }
        if (lane == 63) wsum[w] = x;
        __syncthreads();
        if (w == 0 && lane < 16) {
            int s = wsum[lane];
            #pragma unroll
            for (int off = 1; off < 16; off <<= 1) {
                int y = __shfl_up(s, off, 16);
                if (lane >= off) s += y;
            }
            wsum[lane] = s;
            if (lane == 15) chunk_total = s;
        }
        __syncthreads();
        int wpre = (w == 0) ? 0 : wsum[w - 1];
        if (i < n) {
            int val = carry + wpre + (x - v);
            row[i] = val;
            cur[i] = val;
        }
        carry += chunk_total;
        __syncthreads();
    }
    if (threadIdx.x == 0) row[n] = carry;
}

// ---------------- slim GEMM body: A direct from global, B staged in caller's LDS ----------------

__device__ __forceinline__ void gemm3_body(int mtile, int z, const short* __restrict__ Abf,
                                           int M, const short* __restrict__ wt3,
                                           short* __restrict__ t1b,
                                           uint32* __restrict__ t2q, uint32* __restrict__ t3q,
                                           short* Bs) {   // Bs: 128*136 shorts
    int tid = threadIdx.x;
    int m0 = mtile * 128;
    const short* Bt = wt3 + (size_t)z * D * D;

    #pragma unroll
    for (int i = 0; i < 8; i++) {
        int v = tid + i * 256;
        int row = v >> 4, c8 = v & 15;
        *(short8*)&Bs[row * 136 + c8 * 8] = *(const short8*)(Bt + (size_t)row * D + c8 * 8);
    }
    __syncthreads();

    int wave = tid >> 6, lane = tid & 63;
    int quad = lane >> 4, r16 = lane & 15;
    int mrow = wave * 32;
    int gr0 = m0 + mrow + r16;
    int gr1 = gr0 + 16;

    float4v acc[2][8];
    #pragma unroll
    for (int a = 0; a < 2; a++)
        #pragma unroll
        for (int b = 0; b < 8; b++)
            acc[a][b] = (float4v){0.f, 0.f, 0.f, 0.f};

    #pragma unroll
    for (int kc = 0; kc < 4; kc++) {
        short8 a0 = {0, 0, 0, 0, 0, 0, 0, 0};
        short8 a1 = {0, 0, 0, 0, 0, 0, 0, 0};
        if (gr0 < M) a0 = *(const short8*)(Abf + (size_t)gr0 * D + kc * 32 + quad * 8);
        if (gr1 < M) a1 = *(const short8*)(Abf + (size_t)gr1 * D + kc * 32 + quad * 8);
        #pragma unroll
        for (int nt = 0; nt < 8; nt++) {
            short8 b = *(const short8*)&Bs[(nt * 16 + r16) * 136 + kc * 32 + quad * 8];
            acc[0][nt] = __builtin_amdgcn_mfma_f32_16x16x32_bf16(a0, b, acc[0][nt], 0, 0, 0);
            acc[1][nt] = __builtin_amdgcn_mfma_f32_16x16x32_bf16(a1, b, acc[1][nt], 0, 0, 0);
        }
    }

    #pragma unroll
    for (int rt = 0; rt < 2; rt++)
        #pragma unroll
        for (int reg = 0; reg < 4; reg++) {
            int row = m0 + mrow + rt * 16 + quad * 4 + reg;
            if (row >= M) continue;
            if (z == 0) {
                short8 s8;
                #pragma unroll
                for (int nt = 0; nt < 8; nt++) s8[nt] = (short)f2bf(acc[rt][nt][reg]);
                *(short8*)(t1b + (size_t)row * D + r16 * 8) = s8;
            } else {
                uint32 u0 = __builtin_amdgcn_cvt_pk_fp8_f32(acc[rt][0][reg], acc[rt][1][reg], 0, false);
                u0 = __builtin_amdgcn_cvt_pk_fp8_f32(acc[rt][2][reg], acc[rt][3][reg], u0, true);
                uint32 u1 = __builtin_amdgcn_cvt_pk_fp8_f32(acc[rt][4][reg], acc[rt][5][reg], 0, false);
                u1 = __builtin_amdgcn_cvt_pk_fp8_f32(acc[rt][6][reg], acc[rt][7][reg], u1, true);
                uint32* dq = ((z == 1) ? t2q : t3q) + (size_t)row * 32 + r16 * 2;
                *(uint2*)dq = make_uint2(u0, u1);
            }
        }
}

// ---------------- build: binned edge append (dense stores) + fused layer-0 GEMM ----------------

#define AP_BLOCKS 128

__global__ __launch_bounds__(256)
void build_gemm0(const int* __restrict__ src, const int* __restrict__ dst, int E, int N,
                 int NBK, int* bcur_in, int* bcur_out,
                 uint32* __restrict__ ebuf_in, uint32* __restrict__ ebuf_out,
                 const short* __restrict__ xb, const short* __restrict__ wt,
                 short* __restrict__ t1b, uint32* __restrict__ t2q, uint32* __restrict__ t3q) {
    __shared__ __align__(16) short smem[128 * 136];
    int b = blockIdx.x;
    if (b < AP_BLOCKS) {
        int* h_in = (int*)smem;          // MAXBK
        int* h_out = h_in + MAXBK;       // MAXBK
        for (int i = threadIdx.x; i < 2 * MAXBK; i += 256) h_in[i] = 0;
        __syncthreads();
        int per = (E + AP_BLOCKS - 1) / AP_BLOCKS;
        int lo = b * per, hi = min(E, lo + per);
        for (int e = lo + threadIdx.x; e < hi; e += 256) {
            int s = src[e], d = dst[e];
            atomicAdd(&h_in[d >> 7], 1);
            atomicAdd(&h_out[s >> 7], 1);
        }
        __syncthreads();
        for (int i = threadIdx.x; i < NBK; i += 256) {
            int c = h_in[i];
            h_in[i] = c ? atomicAdd(&bcur_in[i], c) : 0;
            int c2 = h_out[i];
            h_out[i] = c2 ? atomicAdd(&bcur_out[i], c2) : 0;
        }
        __syncthreads();
        for (int e = lo + threadIdx.x; e < hi; e += 256) {
            int s = src[e], d = dst[e];
            int p = atomicAdd(&h_in[d >> 7], 1);
            ebuf_in[p] = ((uint32)s << 7) | (uint32)(d & 127);
            int q = atomicAdd(&h_out[s >> 7], 1);
            ebuf_out[q] = ((uint32)d << 7) | (uint32)(s & 127);
        }
    } else {
        int g = b - AP_BLOCKS;
        gemm3_body(g / 3, g % 3, xb, N, wt, t1b, t2q, t3q, smem);
    }
}

// ---------------- bucket_count_fill: per-bucket degree count + row write + col fill ----------------
// off[k] IS the global exclusive prefix of bucket k, so row[node] = off[k] +
// intra-bucket exclusive prefix of the 128 LDS-counted degrees. All stores
// dense; zero global atomics.

__global__ __launch_bounds__(256)
void bucket_count_fill(const uint32* __restrict__ ebuf_in, const int* __restrict__ off_in,
                       int* __restrict__ row_in, int* __restrict__ col_in,
                       const uint32* __restrict__ ebuf_out, const int* __restrict__ off_out,
                       int* __restrict__ row_out, int* __restrict__ col_out,
                       int N, int NBK) {
    __shared__ int cnt[128];
    __shared__ int incl[128];
    __shared__ int lcur[128];
    int b = blockIdx.x;
    const uint32* ebuf; const int* off; int* row; int* col; int k;
    if (b < NBK) { ebuf = ebuf_in;  off = off_in;  row = row_in;  col = col_in;  k = b; }
    else         { ebuf = ebuf_out; off = off_out; row = row_out; col = col_out; k = b - NBK; }
    int nb = k << 7;
    if (threadIdx.x < 128) cnt[threadIdx.x] = 0;
    __syncthreads();
    int lo = off[k], hi = off[k + 1];
    for (int r = lo + threadIdx.x; r < hi; r += 256) {
        atomicAdd(&cnt[ebuf[r] & 127], 1);
    }
    __syncthreads();
    if (threadIdx.x < 128) {
        int lane = threadIdx.x & 63;
        int v = cnt[threadIdx.x];
        int x = v;
        #pragma unroll
        for (int o = 1; o < 64; o <<= 1) {
            int y = __shfl_up(x, o, 64);
            if (lane >= o) x += y;
        }
        incl[threadIdx.x] = x;
    }
    __syncthreads();
    if (threadIdx.x < 128) {
        int v = cnt[threadIdx.x];
        int add = (threadIdx.x >= 64) ? incl[63] : 0;
        int excl = lo + add + incl[threadIdx.x] - v;
        int node = nb + threadIdx.x;
        if (node < N) row[node] = excl;
        lcur[threadIdx.x] = excl;
        if (k == NBK - 1 && threadIdx.x == 0) row[N] = hi;
    }
    __syncthreads();
    for (int r = lo + threadIdx.x; r < hi; r += 256) {
        uint32 rec = ebuf[r];
        int slot = atomicAdd(&lcur[rec & 127], 1);
        col[slot] = (int)(rec >> 7);
    }
}

__global__ __launch_bounds__(256)
void gemm3_k(const short* __restrict__ hin, int M, const short* __restrict__ wt3,
             short* __restrict__ t1b, uint32* __restrict__ t2q, uint32* __restrict__ t3q) {
    __shared__ __align__(16) short smem[128 * 136];
    gemm3_body(blockIdx.x, blockIdx.z, hin, M, wt3, t1b, t2q, t3q, smem);
}

// ---------------- Final GEMM (MFMA, slim) ----------------

__global__ __launch_bounds__(256)
void gemm_out_mfma(const short* __restrict__ jkb, int M, const short* __restrict__ wlt,
                   const float* __restrict__ blin, float* __restrict__ Cout) {
    __shared__ __align__(16) short Bs[64][136];
    int tid = threadIdx.x;
    int m0 = blockIdx.x * 128;

    #pragma unroll
    for (int i = 0; i < 4; i++) {
        int v = tid + i * 256;
        int row = v >> 4, c8 = v & 15;
        *(short8*)&Bs[row][c8 * 8] = *(const short8*)(wlt + (size_t)row * D + c8 * 8);
    }
    __syncthreads();

    int wave = tid >> 6, lane = tid & 63;
    int quad = lane >> 4, r16 = lane & 15;
    int mrow = wave * 32;
    int gr0 = m0 + mrow + r16;
    int gr1 = gr0 + 16;

    float4v acc[2][4];
    #pragma unroll
    for (int a = 0; a < 2; a++)
        #pragma unroll
        for (int b = 0; b < 4; b++)
            acc[a][b] = (float4v){0.f, 0.f, 0.f, 0.f};

    #pragma unroll
    for (int kc = 0; kc < 4; kc++) {
        short8 a0 = {0, 0, 0, 0, 0, 0, 0, 0};
        short8 a1 = {0, 0, 0, 0, 0, 0, 0, 0};
        if (gr0 < M) a0 = *(const short8*)(jkb + (size_t)gr0 * D + kc * 32 + quad * 8);
        if (gr1 < M) a1 = *(const short8*)(jkb + (size_t)gr1 * D + kc * 32 + quad * 8);
        #pragma unroll
        for (int nt = 0; nt < 4; nt++) {
            short8 b = *(const short8*)&Bs[nt * 16 + r16][kc * 32 + quad * 8];
            acc[0][nt] = __builtin_amdgcn_mfma_f32_16x16x32_bf16(a0, b, acc[0][nt], 0, 0, 0);
            acc[1][nt] = __builtin_amdgcn_mfma_f32_16x16x32_bf16(a1, b, acc[1][nt], 0, 0, 0);
        }
    }

    #pragma unroll
    for (int rt = 0; rt < 2; rt++)
        #pragma unroll
        for (int nt = 0; nt < 4; nt++)
            #pragma unroll
            for (int reg = 0; reg < 4; reg++) {
                int row = m0 + mrow + rt * 16 + quad * 4 + reg;
                int col = nt * 16 + r16;
                if (row < M) Cout[(size_t)row * OUTD + col] = acc[rt][nt][reg] + blin[col];
            }
}

// ---------------- Fused aggregation: fp8 gathers, 2 rows/load, dual-stream ----------------

__global__ __launch_bounds__(256)
void agg_epilogue(const short* __restrict__ t1b,
                  const uint32* __restrict__ t2q, const uint32* __restrict__ t3q,
                  const float* __restrict__ bcombp,
                  const int* __restrict__ row_in, const int* __restrict__ col_in,
                  const int* __restrict__ row_out, const int* __restrict__ col_out,
                  const float* __restrict__ alpha_p,
                  short* __restrict__ h_out, short* __restrict__ jkb,
                  int first, int N) {
    int wv = threadIdx.x >> 6;
    int lane = threadIdx.x & 63;
    int n = blockIdx.x * 4 + wv;
    if (n >= N) return;
    float a = alpha_p[0];
    int s_in = row_in[n], e_in = row_in[n + 1];
    int s_out = row_out[n], e_out = row_out[n + 1];
    int din = e_in - s_in, dout = e_out - s_out;
    bool lower = lane < 32;
    uint32 off32 = lane & 31;

    floatx2 ai0 = {0.f, 0.f}, ai1 = {0.f, 0.f};
    floatx2 ao0 = {0.f, 0.f}, ao1 = {0.f, 0.f};

    int pin = s_in, pout = s_out;
    while (pin < e_in || pout < e_out) {
        int m_in = e_in - pin;   if (m_in > 64) m_in = 64;   if (m_in < 0) m_in = 0;
        int m_out = e_out - pout; if (m_out > 64) m_out = 64; if (m_out < 0) m_out = 0;
        int idxi = (lane < m_in) ? col_in[pin + lane] : 0;
        int idxo = (lane < m_out) ? col_out[pout + lane] : 0;
        int fi = m_in & ~15, fo = m_out & ~15;
        int ji = 0, jo = 0;
        while (ji < fi || jo < fo) {
            uint32 wi[8], wo[8];
            bool di = ji < fi, dw = jo < fo;
            if (di) {
                #pragma unroll
                for (int t = 0; t < 8; t++) {
                    int u0 = __builtin_amdgcn_readlane(idxi, ji + 2 * t);
                    int u1 = __builtin_amdgcn_readlane(idxi, ji + 2 * t + 1);
                    int us = lower ? u0 : u1;
                    wi[t] = t2q[(size_t)us * 32 + off32];
                }
            }
            if (dw) {
                #pragma unroll
                for (int t = 0; t < 8; t++) {
                    int u0 = __builtin_amdgcn_readlane(idxo, jo + 2 * t);
                    int u1 = __builtin_amdgcn_readlane(idxo, jo + 2 * t + 1);
                    int us = lower ? u0 : u1;
                    wo[t] = t3q[(size_t)us * 32 + off32];
                }
            }
            if (di) {
                #pragma unroll
                for (int t = 0; t < 8; t++) {
                    ai0 += __builtin_amdgcn_cvt_pk_f32_fp8(wi[t], false);
                    ai1 += __builtin_amdgcn_cvt_pk_f32_fp8(wi[t], true);
                }
                ji += 16;
            }
            if (dw) {
                #pragma unroll
                for (int t = 0; t < 8; t++) {
                    ao0 += __builtin_amdgcn_cvt_pk_f32_fp8(wo[t], false);
                    ao1 += __builtin_amdgcn_cvt_pk_f32_fp8(wo[t], true);
                }
                jo += 16;
            }
        }
        int ri = m_in - fi, ro = m_out - fo;   // 0..15
        if (ri | ro) {
            uint32 wi[8], wo[8];
            #pragma unroll
            for (int t = 0; t < 8; t++) { wi[t] = 0u; wo[t] = 0u; }
            #pragma unroll
            for (int t = 0; t < 8; t++) {
                if (2 * t < ri) {
                    int j0 = fi + 2 * t;
                    int j1 = (2 * t + 1 < ri) ? j0 + 1 : j0;
                    int u0 = __builtin_amdgcn_readlane(idxi, j0);
                    int u1 = __builtin_amdgcn_readlane(idxi, j1);
                    int us = lower ? u0 : u1;
                    uint32 v = t2q[(size_t)us * 32 + off32];
                    if (2 * t + 1 >= ri) v = lower ? v : 0u;
                    wi[t] = v;
                }
            }
            #pragma unroll
            for (int t = 0; t < 8; t++) {
                if (2 * t < ro) {
                    int j0 = fo + 2 * t;
                    int j1 = (2 * t + 1 < ro) ? j0 + 1 : j0;
                    int u0 = __builtin_amdgcn_readlane(idxo, j0);
                    int u1 = __builtin_amdgcn_readlane(idxo, j1);
                    int us = lower ? u0 : u1;
                    uint32 v = t3q[(size_t)us * 32 + off32];
                    if (2 * t + 1 >= ro) v = lower ? v : 0u;
                    wo[t] = v;
                }
            }
            #pragma unroll
            for (int t = 0; t < 8; t++) {
                ai0 += __builtin_amdgcn_cvt_pk_f32_fp8(wi[t], false);
                ai1 += __builtin_amdgcn_cvt_pk_f32_fp8(wi[t], true);
                ao0 += __builtin_amdgcn_cvt_pk_f32_fp8(wo[t], false);
                ao1 += __builtin_amdgcn_cvt_pk_f32_fp8(wo[t], true);
            }
        }
        pin += m_in; pout += m_out;
    }

    ai0.x += __shfl_xor(ai0.x, 32, 64); ai0.y += __shfl_xor(ai0.y, 32, 64);
    ai1.x += __shfl_xor(ai1.x, 32, 64); ai1.y += __shfl_xor(ai1.y, 32, 64);
    ao0.x += __shfl_xor(ao0.x, 32, 64); ao0.y += __shfl_xor(ao0.y, 32, 64);
    ao1.x += __shfl_xor(ao1.x, 32, 64); ao1.y += __shfl_xor(ao1.y, 32, 64);

    if (lower) {
        float win = (1.0f - a) / (float)max(din, 1);
        float wout = a / (float)max(dout, 1);
        int L = lane;   // 0..31 -> permuted elements 4L..4L+3
        uint2 tv = *(const uint2*)(t1b + (size_t)n * D + 4 * L);
        float4 bc = *(const float4*)(bcombp + 4 * L);
        float t0 = __uint_as_float(tv.x << 16);
        float t1 = __uint_as_float(tv.x & 0xFFFF0000u);
        float t2 = __uint_as_float(tv.y << 16);
        float t3 = __uint_as_float(tv.y & 0xFFFF0000u);
        float h0 = fmaxf(t0 + bc.x + win * ai0.x + wout * ao0.x, 0.f);
        float h1 = fmaxf(t1 + bc.y + win * ai0.y + wout * ao0.y, 0.f);
        float h2 = fmaxf(t2 + bc.z + win * ai1.x + wout * ao1.x, 0.f);
        float h3 = fmaxf(t3 + bc.w + win * ai1.y + wout * ao1.y, 0.f);
        uint32 p0 = (uint32)f2bf(h0) | ((uint32)f2bf(h1) << 16);
        uint32 p1 = (uint32)f2bf(h2) | ((uint32)f2bf(h3) << 16);
        if (h_out) *(uint2*)(h_out + (size_t)n * D + 4 * L) = make_uint2(p0, p1);
        uint2* jp = (uint2*)(jkb + (size_t)n * D + 4 * L);
        if (first) {
            *jp = make_uint2(p0, p1);
        } else {
            uint2 old = *jp;
            uint32 q0 = max(old.x & 0xFFFFu, p0 & 0xFFFFu) | max(old.x & 0xFFFF0000u, p0 & 0xFFFF0000u);
            uint32 q1 = max(old.y & 0xFFFFu, p1 & 0xFFFFu) | max(old.y & 0xFFFF0000u, p1 & 0xFFFF0000u);
            *jp = make_uint2(q0, q1);
        }
    }
}

// ---------------- launch ----------------

extern "C" void kernel_launch(void* const* d_in, const int* in_sizes, int n_in,
                              void* d_out, int out_size, void* d_ws, size_t ws_size,
                              hipStream_t stream) {
    const float* x     = (const float*)d_in[0];
    const int*   ei    = (const int*)d_in[1];
    const float* Wself = (const float*)d_in[2];
    const float* bself = (const float*)d_in[3];
    const float* Wstd  = (const float*)d_in[4];
    const float* bstd  = (const float*)d_in[5];
    const float* Wdts  = (const float*)d_in[6];
    const float* bdts  = (const float*)d_in[7];
    const float* Wlin  = (const float*)d_in[8];
    const float* blin  = (const float*)d_in[9];
    const float* alpha = (const float*)d_in[10];

    int N = in_sizes[0] / D;   // 50000
    int E = in_sizes[1] / 2;   // 800000
    int NBK = ceil_div(N, 128);

    char* p = (char*)d_ws;
    auto alloc = [&](size_t bytes) {
        char* q = p;
        p += (bytes + 255) & ~(size_t)255;
        return q;
    };
    // zero-init region: bucket counts only (single 4KB memset)
    int* bc_in   = (int*)alloc((size_t)MAXBK * 4);
    int* bc_out  = (int*)alloc((size_t)MAXBK * 4);
    char* zero_end = p;
    int* row_in   = (int*)alloc((size_t)(N + 1) * 4);
    int* row_out  = (int*)alloc((size_t)(N + 1) * 4);
    int* off_in   = (int*)alloc((size_t)(MAXBK + 1) * 4);
    int* off_out  = (int*)alloc((size_t)(MAXBK + 1) * 4);
    int* bcur_in  = (int*)alloc((size_t)(MAXBK + 1) * 4);
    int* bcur_out = (int*)alloc((size_t)(MAXBK + 1) * 4);
    uint32* ebuf_in  = (uint32*)alloc((size_t)E * 4);
    uint32* ebuf_out = (uint32*)alloc((size_t)E * 4);
    int* col_in  = (int*)alloc((size_t)E * 4);
    int* col_out = (int*)alloc((size_t)E * 4);
    short* xb    = (short*)alloc((size_t)N * D * 2);
    short* hb    = (short*)alloc((size_t)N * D * 2);
    short* wt    = (short*)alloc((size_t)9 * D * D * 2);
    short* wlt   = (short*)alloc((size_t)D * OUTD * 2);
    float* bcombp = (float*)alloc((size_t)LAYERS * D * 4);
    short* t1b   = (short*)alloc((size_t)N * D * 2);
    uint32* t2q  = (uint32*)alloc((size_t)N * 32 * 4);   // fp8, 128 B/row
    uint32* t3q  = (uint32*)alloc((size_t)N * 32 * 4);
    short* jkb   = (short*)alloc((size_t)N * D * 2);

    const int* srcp = ei;
    const int* dstp = ei + E;

    hipMemsetAsync(bc_in, 0, (size_t)(zero_end - (char*)bc_in), stream);

    prep<<<BH_BLOCKS + CVX_BLOCKS + 11, 256, 0, stream>>>(
        srcp, dstp, E, N, NBK, bc_in, bc_out, x, xb,
        Wself, Wstd, Wdts, Wlin, bself, bstd, bdts, alpha, wt, wlt, bcombp);
    scan2<<<2, 1024, 0, stream>>>(bc_in, off_in, bcur_in, bc_out, off_out, bcur_out, NBK);

    int gm = ceil_div(N, 128);
    build_gemm0<<<AP_BLOCKS + 3 * gm, 256, 0, stream>>>(
        srcp, dstp, E, N, NBK, bcur_in, bcur_out, ebuf_in, ebuf_out,
        xb, wt, t1b, t2q, t3q);
    bucket_count_fill<<<2 * NBK, 256, 0, stream>>>(ebuf_in, off_in, row_in, col_in,
                                                   ebuf_out, off_out, row_out, col_out, N, NBK);

    for (int l = 0; l < LAYERS; l++) {
        agg_epilogue<<<ceil_div(N, 4), 256, 0, stream>>>(
            t1b, t2q, t3q, bcombp + (size_t)l * D,
            row_in, col_in, row_out, col_out, alpha,
            (l == LAYERS - 1) ? nullptr : hb, jkb, (l == 0) ? 1 : 0, N);
        if (l < LAYERS - 1)
            gemm3_k<<<dim3(gm, 1, 3), 256, 0, stream>>>(hb, N, wt + (size_t)(l + 1) * 3 * D * D,
                                                        t1b, t2q, t3q);
    }
    gemm_out_mfma<<<gm, 256, 0, stream>>>(jkb, N, wlt, blin, (float*)d_out);
}

// Round 10
// 329.400 us; speedup vs baseline: 1.5975x; 1.1104x over previous
//
#include <hip/hip_runtime.h>

#define D 128
#define OUTD 64
#define LAYERS 3
#define MAXBK 512   // max buckets (node>>7); N=50000 -> 391

typedef __attribute__((ext_vector_type(8))) short short8;
typedef __attribute__((ext_vector_type(4))) float float4v;
typedef __attribute__((ext_vector_type(2))) float floatx2;
typedef unsigned int uint32;

static inline int ceil_div(int a, int b) { return (a + b - 1) / b; }

__device__ __forceinline__ unsigned short f2bf(float f) {
    unsigned int u = __float_as_uint(f);
    unsigned int r = u + 0x7FFFu + ((u >> 16) & 1u);
    return (unsigned short)(r >> 16);
}

// feature permutation: storage element position of logical feature f.
__device__ __forceinline__ int fperm(int f) { return (f & 15) * 8 + (f >> 4); }

// ---------------- prep: combined bucket hist + all converts ----------------

#define BH_BLOCKS  64
#define CVX_BLOCKS 1044

__global__ __launch_bounds__(256)
void prep(const int* __restrict__ src, const int* __restrict__ dst, int E, int N, int NBK,
          int* bc,
          const float* __restrict__ x, short* __restrict__ xb,
          const float* __restrict__ Wself, const float* __restrict__ Wstd,
          const float* __restrict__ Wdts, const float* __restrict__ Wlin,
          const float* __restrict__ bself, const float* __restrict__ bstd,
          const float* __restrict__ bdts, const float* __restrict__ alpha_p,
          short* __restrict__ wt, short* __restrict__ wlt, float* __restrict__ bcombp) {
    __shared__ int bh[MAXBK];
    int b = blockIdx.x;
    if (b < BH_BLOCKS) {
        // combined per-bucket record counts (in + out records land in dest/src node buckets)
        for (int i = threadIdx.x; i < MAXBK; i += 256) bh[i] = 0;
        __syncthreads();
        int per = (E + BH_BLOCKS - 1) / BH_BLOCKS;
        int lo = b * per, hi = min(E, lo + per);
        for (int e = lo + threadIdx.x; e < hi; e += 256) {
            int s = src[e], d = dst[e];
            atomicAdd(&bh[d >> 7], 1);
            atomicAdd(&bh[s >> 7], 1);
        }
        __syncthreads();
        for (int i = threadIdx.x; i < NBK; i += 256) {
            if (bh[i]) atomicAdd(&bc[i], bh[i]);
        }
    } else if (b < BH_BLOCKS + CVX_BLOCKS) {
        int total = N * 16;
        for (int i = (b - BH_BLOCKS) * 256 + threadIdx.x; i < total; i += CVX_BLOCKS * 256) {
            int n = i >> 4, q = i & 15;
            const float* xr = x + (size_t)n * D + q;
            short8 s;
            #pragma unroll
            for (int fh = 0; fh < 8; fh++) s[fh] = (short)f2bf(xr[fh * 16]);
            *(short8*)(xb + (size_t)n * D + q * 8) = s;
        }
    } else {
        int cb = b - BH_BLOCKS - CVX_BLOCKS;   // 0..10
        if (cb < 9) {
            int l = cb / 3, m = cb % 3;
            const float* W = (m == 0 ? Wself : (m == 1 ? Wstd : Wdts)) + (size_t)l * D * D;
            short* o = wt + (size_t)cb * D * D;
            for (int idx = threadIdx.x; idx < D * D; idx += 256) {
                int k = idx >> 7, n = idx & 127;
                o[n * D + fperm(k)] = (short)f2bf(W[idx]);
            }
        } else if (cb == 9) {
            for (int idx = threadIdx.x; idx < D * OUTD; idx += 256) {
                int k = idx >> 6, n = idx & 63;
                wlt[n * D + fperm(k)] = (short)f2bf(Wlin[idx]);
            }
        } else {
            float a = alpha_p[0];
            for (int i = threadIdx.x; i < LAYERS * D; i += 256) {
                int l = i >> 7, j = i & 127;
                bcombp[l * D + fperm(j)] = bself[i] + (1.0f - a) * bstd[i] + a * bdts[i];
            }
        }
    }
}

// ---------------- scan over NBK buckets (NBK <= 512 fits one 1024-block pass) ----------------

__global__ __launch_bounds__(1024)
void scan1(const int* __restrict__ bc, int* __restrict__ off, int* __restrict__ bcur, int n) {
    __shared__ int wsum[16];
    __shared__ int total;
    int tid = threadIdx.x, lane = tid & 63, w = tid >> 6;
    int v = (tid < n) ? bc[tid] : 0;
    int x = v;
    #pragma unroll
    for (int o = 1; o < 64; o <<= 1) {
        int y = __shfl_up(x, o, 64);
        if (lane >= o) x += y;
    }
    if (lane == 63) wsum[w] = x;
    __syncthreads();
    if (w == 0 && lane < 16) {
        int s = wsum[lane];
        #pragma unroll
        for (int o = 1; o < 16; o <<= 1) {
            int y = __shfl_up(s, o, 16);
            if (lane >= o) s += y;
        }
        wsum[lane] = s;
        if (lane == 15) total = s;
    }
    __syncthreads();
    int wpre = w ? wsum[w - 1] : 0;
    if (tid < n) {
        int e = wpre + x - v;
        off[tid] = e;
        bcur[tid] = e;
    }
    if (tid == 0) off[n] = total;
}

// ---------------- slim GEMM body: A direct from global, B staged in caller's LDS ----------------

__device__ __forceinline__ void gemm3_body(int mtile, int z, const short* __restrict__ Abf,
                                           int M, const short* __restrict__ wt3,
                                           short* __restrict__ t1b,
                                           uint32* __restrict__ t2q, uint32* __restrict__ t3q,
                                           short* Bs) {   // Bs: 128*136 shorts
    int tid = threadIdx.x;
    int m0 = mtile * 128;
    const short* Bt = wt3 + (size_t)z * D * D;

    #pragma unroll
    for (int i = 0; i < 8; i++) {
        int v = tid + i * 256;
        int row = v >> 4, c8 = v & 15;
        *(short8*)&Bs[row * 136 + c8 * 8] = *(const short8*)(Bt + (size_t)row * D + c8 * 8);
    }
    __syncthreads();

    int wave = tid >> 6, lane = tid & 63;
    int quad = lane >> 4, r16 = lane & 15;
    int mrow = wave * 32;
    int gr0 = m0 + mrow + r16;
    int gr1 = gr0 + 16;

    float4v acc[2][8];
    #pragma unroll
    for (int a = 0; a < 2; a++)
        #pragma unroll
        for (int b = 0; b < 8; b++)
            acc[a][b] = (float4v){0.f, 0.f, 0.f, 0.f};

    #pragma unroll
    for (int kc = 0; kc < 4; kc++) {
        short8 a0 = {0, 0, 0, 0, 0, 0, 0, 0};
        short8 a1 = {0, 0, 0, 0, 0, 0, 0, 0};
        if (gr0 < M) a0 = *(const short8*)(Abf + (size_t)gr0 * D + kc * 32 + quad * 8);
        if (gr1 < M) a1 = *(const short8*)(Abf + (size_t)gr1 * D + kc * 32 + quad * 8);
        #pragma unroll
        for (int nt = 0; nt < 8; nt++) {
            short8 b = *(const short8*)&Bs[(nt * 16 + r16) * 136 + kc * 32 + quad * 8];
            acc[0][nt] = __builtin_amdgcn_mfma_f32_16x16x32_bf16(a0, b, acc[0][nt], 0, 0, 0);
            acc[1][nt] = __builtin_amdgcn_mfma_f32_16x16x32_bf16(a1, b, acc[1][nt], 0, 0, 0);
        }
    }

    #pragma unroll
    for (int rt = 0; rt < 2; rt++)
        #pragma unroll
        for (int reg = 0; reg < 4; reg++) {
            int row = m0 + mrow + rt * 16 + quad * 4 + reg;
            if (row >= M) continue;
            if (z == 0) {
                short8 s8;
                #pragma unroll
                for (int nt = 0; nt < 8; nt++) s8[nt] = (short)f2bf(acc[rt][nt][reg]);
                *(short8*)(t1b + (size_t)row * D + r16 * 8) = s8;
            } else {
                uint32 u0 = __builtin_amdgcn_cvt_pk_fp8_f32(acc[rt][0][reg], acc[rt][1][reg], 0, false);
                u0 = __builtin_amdgcn_cvt_pk_fp8_f32(acc[rt][2][reg], acc[rt][3][reg], u0, true);
                uint32 u1 = __builtin_amdgcn_cvt_pk_fp8_f32(acc[rt][4][reg], acc[rt][5][reg], 0, false);
                u1 = __builtin_amdgcn_cvt_pk_fp8_f32(acc[rt][6][reg], acc[rt][7][reg], u1, true);
                uint32* dq = ((z == 1) ? t2q : t3q) + (size_t)row * 32 + r16 * 2;
                *(uint2*)dq = make_uint2(u0, u1);
            }
        }
}

// ---------------- build: binned edge append (combined records) + fused layer-0 GEMM ----------------
// record = payload << 7 | (node & 127); payload = src (in-edge, gather t2q) or
// dst + N (out-edge, gather t3q). t2q/t3q contiguous -> payload IS the row index.

#define AP_BLOCKS 128

__global__ __launch_bounds__(256)
void build_gemm0(const int* __restrict__ src, const int* __restrict__ dst, int E, int N,
                 int NBK, int* bcur, uint32* __restrict__ ebuf,
                 const short* __restrict__ xb, const short* __restrict__ wt,
                 short* __restrict__ t1b, uint32* __restrict__ t2q, uint32* __restrict__ t3q) {
    __shared__ __align__(16) short smem[128 * 136];
    int b = blockIdx.x;
    if (b < AP_BLOCKS) {
        int* h = (int*)smem;          // MAXBK ints
        for (int i = threadIdx.x; i < MAXBK; i += 256) h[i] = 0;
        __syncthreads();
        int per = (E + AP_BLOCKS - 1) / AP_BLOCKS;
        int lo = b * per, hi = min(E, lo + per);
        for (int e = lo + threadIdx.x; e < hi; e += 256) {
            int s = src[e], d = dst[e];
            atomicAdd(&h[d >> 7], 1);
            atomicAdd(&h[s >> 7], 1);
        }
        __syncthreads();
        for (int i = threadIdx.x; i < NBK; i += 256) {
            int c = h[i];
            h[i] = c ? atomicAdd(&bcur[i], c) : 0;
        }
        __syncthreads();
        for (int e = lo + threadIdx.x; e < hi; e += 256) {
            int s = src[e], d = dst[e];
            int p = atomicAdd(&h[d >> 7], 1);
            ebuf[p] = ((uint32)s << 7) | (uint32)(d & 127);
            int q = atomicAdd(&h[s >> 7], 1);
            ebuf[q] = ((uint32)(d + N) << 7) | (uint32)(s & 127);
        }
    } else {
        int g = b - AP_BLOCKS;
        gemm3_body(g / 3, g % 3, xb, N, wt, t1b, t2q, t3q, smem);
    }
}

// ---------------- bucket_count_fill: per-(node,tag) count + rowx write + col fill ----------------
// rowx[2n] = in-segment start, rowx[2n+1] = out-segment start, rowx[2n+2] = end.
// In-records (payload < N) sorted before out-records per node.

__global__ __launch_bounds__(256)
void bucket_count_fill(const uint32* __restrict__ ebuf, const int* __restrict__ off,
                       int* __restrict__ rowx, int* __restrict__ col, int N, int NBK) {
    __shared__ int cnt[256];
    __shared__ int wsum4[4];
    __shared__ int lcur[256];
    int k = blockIdx.x;
    int nb = k << 7;
    int tid = threadIdx.x;
    cnt[tid] = 0;
    __syncthreads();
    int lo = off[k], hi = off[k + 1];
    for (int r = lo + tid; r < hi; r += 256) {
        uint32 rec = ebuf[r];
        int t = ((rec >> 7) >= (uint32)N) ? 1 : 0;
        atomicAdd(&cnt[((rec & 127u) << 1) | t], 1);
    }
    __syncthreads();
    int lane = tid & 63, w = tid >> 6;
    int v = cnt[tid];
    int x = v;
    #pragma unroll
    for (int o = 1; o < 64; o <<= 1) {
        int y = __shfl_up(x, o, 64);
        if (lane >= o) x += y;
    }
    if (lane == 63) wsum4[w] = x;
    __syncthreads();
    if (tid == 0) {
        int s = 0;
        #pragma unroll
        for (int i = 0; i < 4; i++) { int t = wsum4[i]; wsum4[i] = s; s += t; }
    }
    __syncthreads();
    int excl = lo + wsum4[w] + x - v;
    int node = nb + (tid >> 1);
    if (node < N) rowx[(node << 1) | (tid & 1)] = excl;
    lcur[tid] = excl;
    if (k == NBK - 1 && tid == 0) rowx[2 * N] = hi;
    __syncthreads();
    for (int r = lo + tid; r < hi; r += 256) {
        uint32 rec = ebuf[r];
        int t = ((rec >> 7) >= (uint32)N) ? 1 : 0;
        int slot = atomicAdd(&lcur[((rec & 127u) << 1) | t], 1);
        col[slot] = (int)(rec >> 7);
    }
}

__global__ __launch_bounds__(256)
void gemm3_k(const short* __restrict__ hin, int M, const short* __restrict__ wt3,
             short* __restrict__ t1b, uint32* __restrict__ t2q, uint32* __restrict__ t3q) {
    __shared__ __align__(16) short smem[128 * 136];
    gemm3_body(blockIdx.x, blockIdx.z, hin, M, wt3, t1b, t2q, t3q, smem);
}

// ---------------- Final GEMM (MFMA, slim) ----------------

__global__ __launch_bounds__(256)
void gemm_out_mfma(const short* __restrict__ jkb, int M, const short* __restrict__ wlt,
                   const float* __restrict__ blin, float* __restrict__ Cout) {
    __shared__ __align__(16) short Bs[64][136];
    int tid = threadIdx.x;
    int m0 = blockIdx.x * 128;

    #pragma unroll
    for (int i = 0; i < 4; i++) {
        int v = tid + i * 256;
        int row = v >> 4, c8 = v & 15;
        *(short8*)&Bs[row][c8 * 8] = *(const short8*)(wlt + (size_t)row * D + c8 * 8);
    }
    __syncthreads();

    int wave = tid >> 6, lane = tid & 63;
    int quad = lane >> 4, r16 = lane & 15;
    int mrow = wave * 32;
    int gr0 = m0 + mrow + r16;
    int gr1 = gr0 + 16;

    float4v acc[2][4];
    #pragma unroll
    for (int a = 0; a < 2; a++)
        #pragma unroll
        for (int b = 0; b < 4; b++)
            acc[a][b] = (float4v){0.f, 0.f, 0.f, 0.f};

    #pragma unroll
    for (int kc = 0; kc < 4; kc++) {
        short8 a0 = {0, 0, 0, 0, 0, 0, 0, 0};
        short8 a1 = {0, 0, 0, 0, 0, 0, 0, 0};
        if (gr0 < M) a0 = *(const short8*)(jkb + (size_t)gr0 * D + kc * 32 + quad * 8);
        if (gr1 < M) a1 = *(const short8*)(jkb + (size_t)gr1 * D + kc * 32 + quad * 8);
        #pragma unroll
        for (int nt = 0; nt < 4; nt++) {
            short8 b = *(const short8*)&Bs[nt * 16 + r16][kc * 32 + quad * 8];
            acc[0][nt] = __builtin_amdgcn_mfma_f32_16x16x32_bf16(a0, b, acc[0][nt], 0, 0, 0);
            acc[1][nt] = __builtin_amdgcn_mfma_f32_16x16x32_bf16(a1, b, acc[1][nt], 0, 0, 0);
        }
    }

    #pragma unroll
    for (int rt = 0; rt < 2; rt++)
        #pragma unroll
        for (int nt = 0; nt < 4; nt++)
            #pragma unroll
            for (int reg = 0; reg < 4; reg++) {
                int row = m0 + mrow + rt * 16 + quad * 4 + reg;
                int col = nt * 16 + r16;
                if (row < M) Cout[(size_t)row * OUTD + col] = acc[rt][nt][reg] + blin[col];
            }
}

// ---------------- Fused aggregation: combined stream, weight-fma, uint2 gathers ----------------
// One wave per node. Combined segment [in | out]; per-lane weight vector built
// once per 64-edge chunk (win for in-positions, wout for out, 0 beyond end) ->
// tails need NO special handling. 4 rows per wave-load (lane: row lane>>4,
// uint2 chunk lane&15). Row index + weight broadcast via 2 shfl (bpermute).

__global__ __launch_bounds__(256)
void agg_epilogue(const short* __restrict__ t1b,
                  const uint32* __restrict__ tq,       // 2N fp8 rows (t2q|t3q)
                  const float* __restrict__ bcombp,
                  const int* __restrict__ rowx, const int* __restrict__ col,
                  const float* __restrict__ alpha_p,
                  short* __restrict__ h_out, short* __restrict__ jkb,
                  int first, int N) {
    int wv = threadIdx.x >> 6;
    int lane = threadIdx.x & 63;
    int n = blockIdx.x * 4 + wv;
    if (n >= N) return;
    float a = alpha_p[0];
    int2 r01 = *(const int2*)(rowx + 2 * n);
    int r0 = r01.x, r1 = r01.y, r2 = rowx[2 * n + 2];
    float win = (1.0f - a) / (float)max(r1 - r0, 1);
    float wout = a / (float)max(r2 - r1, 1);
    int rgrp = lane >> 4;
    int c = lane & 15;
    int boff = c * 2;   // uint index within 32-uint row

    floatx2 A0 = {0.f, 0.f}, A1 = {0.f, 0.f}, A2 = {0.f, 0.f}, A3 = {0.f, 0.f};

    for (int p = r0; p < r2; p += 64) {
        int m = r2 - p;
        if (m > 64) m = 64;
        int e = p + lane;
        int idx = (lane < m) ? col[e] : 0;
        float wgt = (lane < m) ? ((e < r1) ? win : wout) : 0.f;
        for (int k = 0; k < m; k += 16) {
            #pragma unroll
            for (int j = 0; j < 4; j++) {
                if (k + 4 * j < m) {
                    int kk = k + 4 * j + rgrp;
                    int rec = __shfl(idx, kk, 64);
                    float ww = __shfl(wgt, kk, 64);
                    uint2 v = *(const uint2*)(tq + (size_t)rec * 32 + boff);
                    floatx2 wv2 = {ww, ww};
                    A0 += wv2 * __builtin_amdgcn_cvt_pk_f32_fp8(v.x, false);
                    A1 += wv2 * __builtin_amdgcn_cvt_pk_f32_fp8(v.x, true);
                    A2 += wv2 * __builtin_amdgcn_cvt_pk_f32_fp8(v.y, false);
                    A3 += wv2 * __builtin_amdgcn_cvt_pk_f32_fp8(v.y, true);
                }
            }
        }
    }

    // reduce across the 4 row-groups (same feature chunk c)
    #define RED(X) \
        X.x += __shfl_xor(X.x, 16, 64); X.y += __shfl_xor(X.y, 16, 64); \
        X.x += __shfl_xor(X.x, 32, 64); X.y += __shfl_xor(X.y, 32, 64);
    RED(A0) RED(A1) RED(A2) RED(A3)
    #undef RED

    if (lane < 16) {
        // lane c owns permuted elements c*8 .. c*8+7
        uint4 tv = *(const uint4*)(t1b + (size_t)n * D + c * 8);
        float4 b0 = *(const float4*)(bcombp + c * 8);
        float4 b1 = *(const float4*)(bcombp + c * 8 + 4);
        float h0 = fmaxf(__uint_as_float(tv.x << 16)          + b0.x + A0.x, 0.f);
        float h1 = fmaxf(__uint_as_float(tv.x & 0xFFFF0000u)  + b0.y + A0.y, 0.f);
        float h2 = fmaxf(__uint_as_float(tv.y << 16)          + b0.z + A1.x, 0.f);
        float h3 = fmaxf(__uint_as_float(tv.y & 0xFFFF0000u)  + b0.w + A1.y, 0.f);
        float h4 = fmaxf(__uint_as_float(tv.z << 16)          + b1.x + A2.x, 0.f);
        float h5 = fmaxf(__uint_as_float(tv.z & 0xFFFF0000u)  + b1.y + A2.y, 0.f);
        float h6 = fmaxf(__uint_as_float(tv.w << 16)          + b1.z + A3.x, 0.f);
        float h7 = fmaxf(__uint_as_float(tv.w & 0xFFFF0000u)  + b1.w + A3.y, 0.f);
        uint32 p0 = (uint32)f2bf(h0) | ((uint32)f2bf(h1) << 16);
        uint32 p1 = (uint32)f2bf(h2) | ((uint32)f2bf(h3) << 16);
        uint32 p2 = (uint32)f2bf(h4) | ((uint32)f2bf(h5) << 16);
        uint32 p3 = (uint32)f2bf(h6) | ((uint32)f2bf(h7) << 16);
        uint4 pk = make_uint4(p0, p1, p2, p3);
        if (h_out) *(uint4*)(h_out + (size_t)n * D + c * 8) = pk;
        uint4* jp = (uint4*)(jkb + (size_t)n * D + c * 8);
        if (first) {
            *jp = pk;
        } else {
            uint4 old = *jp;
            // relu'd bf16 >= 0 -> monotone as u16; per-half max
            uint32 q0 = max(old.x & 0xFFFFu, pk.x & 0xFFFFu) | max(old.x & 0xFFFF0000u, pk.x & 0xFFFF0000u);
            uint32 q1 = max(old.y & 0xFFFFu, pk.y & 0xFFFFu) | max(old.y & 0xFFFF0000u, pk.y & 0xFFFF0000u);
            uint32 q2 = max(old.z & 0xFFFFu, pk.z & 0xFFFFu) | max(old.z & 0xFFFF0000u, pk.z & 0xFFFF0000u);
            uint32 q3 = max(old.w & 0xFFFFu, pk.w & 0xFFFFu) | max(old.w & 0xFFFF0000u, pk.w & 0xFFFF0000u);
            *jp = make_uint4(q0, q1, q2, q3);
        }
    }
}

// ---------------- launch ----------------

extern "C" void kernel_launch(void* const* d_in, const int* in_sizes, int n_in,
                              void* d_out, int out_size, void* d_ws, size_t ws_size,
                              hipStream_t stream) {
    const float* x     = (const float*)d_in[0];
    const int*   ei    = (const int*)d_in[1];
    const float* Wself = (const float*)d_in[2];
    const float* bself = (const float*)d_in[3];
    const float* Wstd  = (const float*)d_in[4];
    const float* bstd  = (const float*)d_in[5];
    const float* Wdts  = (const float*)d_in[6];
    const float* bdts  = (const float*)d_in[7];
    const float* Wlin  = (const float*)d_in[8];
    const float* blin  = (const float*)d_in[9];
    const float* alpha = (const float*)d_in[10];

    int N = in_sizes[0] / D;   // 50000
    int E = in_sizes[1] / 2;   // 800000
    int NBK = ceil_div(N, 128);

    char* p = (char*)d_ws;
    auto alloc = [&](size_t bytes) {
        char* q = p;
        p += (bytes + 255) & ~(size_t)255;
        return q;
    };
    int* bc    = (int*)alloc((size_t)MAXBK * 4);       // zeroed
    char* zero_end = p;
    int* off   = (int*)alloc((size_t)(MAXBK + 1) * 4);
    int* bcur  = (int*)alloc((size_t)(MAXBK + 1) * 4);
    int* rowx  = (int*)alloc((size_t)(2 * N + 2) * 4);
    uint32* ebuf = (uint32*)alloc((size_t)2 * E * 4);
    int* col   = (int*)alloc((size_t)(2 * E + 64) * 4);
    short* xb    = (short*)alloc((size_t)N * D * 2);
    short* hb    = (short*)alloc((size_t)N * D * 2);
    short* wt    = (short*)alloc((size_t)9 * D * D * 2);
    short* wlt   = (short*)alloc((size_t)D * OUTD * 2);
    float* bcombp = (float*)alloc((size_t)LAYERS * D * 4);
    short* t1b   = (short*)alloc((size_t)N * D * 2);
    uint32* tq   = (uint32*)alloc((size_t)2 * N * 32 * 4);  // fp8 rows: [t2q | t3q]
    short* jkb   = (short*)alloc((size_t)N * D * 2);

    uint32* t2q = tq;
    uint32* t3q = tq + (size_t)N * 32;

    const int* srcp = ei;
    const int* dstp = ei + E;

    hipMemsetAsync(bc, 0, (size_t)(zero_end - (char*)bc), stream);

    prep<<<BH_BLOCKS + CVX_BLOCKS + 11, 256, 0, stream>>>(
        srcp, dstp, E, N, NBK, bc, x, xb,
        Wself, Wstd, Wdts, Wlin, bself, bstd, bdts, alpha, wt, wlt, bcombp);
    scan1<<<1, 1024, 0, stream>>>(bc, off, bcur, NBK);

    int gm = ceil_div(N, 128);
    build_gemm0<<<AP_BLOCKS + 3 * gm, 256, 0, stream>>>(
        srcp, dstp, E, N, NBK, bcur, ebuf, xb, wt, t1b, t2q, t3q);
    bucket_count_fill<<<NBK, 256, 0, stream>>>(ebuf, off, rowx, col, N, NBK);

    for (int l = 0; l < LAYERS; l++) {
        agg_epilogue<<<ceil_div(N, 4), 256, 0, stream>>>(
            t1b, tq, bcombp + (size_t)l * D, rowx, col, alpha,
            (l == LAYERS - 1) ? nullptr : hb, jkb, (l == 0) ? 1 : 0, N);
        if (l < LAYERS - 1)
            gemm3_k<<<dim3(gm, 1, 3), 256, 0, stream>>>(hb, N, wt + (size_t)(l + 1) * 3 * D * D,
                                                        t1b, t2q, t3q);
    }
    gemm_out_mfma<<<gm, 256, 0, stream>>>(jkb, N, wlt, blin, (float*)d_out);
}